// Round 3
// baseline (2422.701 us; speedup 1.0000x reference)
//
#include <hip/hip_runtime.h>

typedef unsigned short u16;
typedef unsigned int u32;

constexpr int H_ = 64;
constexpr int W_ = 256;
constexpr int HW_ = H_ * W_;

__device__ __forceinline__ float bf2f(u16 v) { return __uint_as_float(((u32)v) << 16); }
__device__ __forceinline__ u16 f2bf(float f) {
  u32 x = __float_as_uint(f);
  u32 r = (x + 0x7fffu + ((x >> 16) & 1u)) >> 16;
  return (u16)r;
}
__device__ __forceinline__ float lo2f(u32 p) { return __uint_as_float(p << 16); }
__device__ __forceinline__ float hi2f(u32 p) { return __uint_as_float(p & 0xffff0000u); }
__device__ __forceinline__ void unpack8(uint4 v, float* f) {
  f[0] = lo2f(v.x); f[1] = hi2f(v.x);
  f[2] = lo2f(v.y); f[3] = hi2f(v.y);
  f[4] = lo2f(v.z); f[5] = hi2f(v.z);
  f[6] = lo2f(v.w); f[7] = hi2f(v.w);
}

// ---------------- normalize all f32 inputs to a bf16 arena ----------------
constexpr int NT = 26;
constexpr int ELEMS_PER_BLK = 4096;
struct CvtArgs {
  const void* src[NT];
  u32 dst_off[NT];   // u16 elements
  u32 n[NT];         // element count
  u32 blk_start[NT]; // ascending
};

__global__ void convert_all(CvtArgs a, u16* __restrict__ dst) {
  const u32 bid = blockIdx.x;
  int ti = 0;
#pragma unroll
  for (int k = 1; k < NT; ++k) if (a.blk_start[k] <= bid) ti = k;
  const u32 e0 = (bid - a.blk_start[ti]) * ELEMS_PER_BLK;
  const u32 n = a.n[ti];
  u32 hi = e0 + ELEMS_PER_BLK; if (hi > n) hi = n;
  const float* sp = (const float*)a.src[ti];
  u16* d = dst + a.dst_off[ti];
  for (u32 i = e0 + threadIdx.x; i < hi; i += 256) d[i] = f2bf(sp[i]);
}

// ---------------- 1x1-conv GEMM over positions ----------------
// out[b,o,p] = act(sum_c w[o,c]*x[b,c,p] + bias[o]) (+res)
// RES: 0 none, 2 bf16 single, 3 f32 single, 4 f32 dual (cat batch: b<2->resA, else resB)
template <int CIN, int COUT, int POS, bool LN, bool SILU, bool IN_F32, int RES, bool OUT_F32>
__launch_bounds__(256)
__global__ void gemm1x1(const void* __restrict__ xA, const void* __restrict__ xB,
                        const u16* __restrict__ w, const u16* __restrict__ bias,
                        const u16* __restrict__ lng, const u16* __restrict__ lnb, float lneps,
                        const void* __restrict__ resA, const void* __restrict__ resB,
                        void* __restrict__ out, int b_off) {
  static_assert(!LN || (CIN == 128 && POS == 64), "LN path assumes CIN=128, POS=64");
  constexpr int PITCH = CIN + 8;
  __shared__ __align__(16) u16 xs[POS * PITCH];
  const int t = threadIdx.x;
  const int b = blockIdx.y;           // x batch
  const int bo2 = b + b_off;          // res/out batch
  const int pos0 = blockIdx.x * POS;

  const u16* xb16 = nullptr;
  const float* xf32 = nullptr;
  if constexpr (IN_F32) {
    xf32 = ((const float*)xA) + (size_t)b * CIN * HW_;
  } else {
    const u16* basep = (const u16*)((xB != nullptr && b >= 2) ? xB : xA);
    const int bb = (xB != nullptr) ? ((b < 2) ? b : b - 2) : b;
    xb16 = basep + (size_t)bb * CIN * HW_;
  }

  for (int idx = t; idx < CIN * POS; idx += 256) {
    int c = idx / POS, p = idx % POS;
    u16 v;
    if constexpr (IN_F32) v = f2bf(xf32[(size_t)c * HW_ + pos0 + p]);
    else                  v = xb16[(size_t)c * HW_ + pos0 + p];
    xs[p * PITCH + c] = v;
  }
  __syncthreads();

  if constexpr (LN) {
    __shared__ float red1[256], red2[256], stm[64], str[64];
    const int p = t & 63, part = t >> 6;
    float s = 0.f, sq = 0.f;
#pragma unroll
    for (int k = 0; k < 32; k += 8) {
      uint4 v = *(const uint4*)(xs + p * PITCH + part * 32 + k);
      float f[8]; unpack8(v, f);
#pragma unroll
      for (int j = 0; j < 8; ++j) { s += f[j]; sq += f[j] * f[j]; }
    }
    red1[part * 64 + p] = s; red2[part * 64 + p] = sq;
    __syncthreads();
    if (t < 64) {
      float ss = red1[t] + red1[64 + t] + red1[128 + t] + red1[192 + t];
      float qq = red2[t] + red2[64 + t] + red2[128 + t] + red2[192 + t];
      float m = ss * (1.0f / CIN);
      float var = qq * (1.0f / CIN) - m * m;
      var = var < 0.f ? 0.f : var;
      stm[t] = m; str[t] = rsqrtf(var + lneps);
    }
    __syncthreads();
    const float m = stm[p], r = str[p];
#pragma unroll
    for (int k = 0; k < 32; k += 8) {
      const int c = part * 32 + k;
      uint4 v = *(const uint4*)(xs + p * PITCH + c);
      float f[8]; unpack8(v, f);
      u32 pk[4];
#pragma unroll
      for (int j = 0; j < 8; j += 2) {
        float g0 = bf2f(lng[c + j]), be0 = bf2f(lnb[c + j]);
        float g1 = bf2f(lng[c + j + 1]), be1 = bf2f(lnb[c + j + 1]);
        u16 lo = f2bf((f[j] - m) * r * g0 + be0);
        u16 hi = f2bf((f[j + 1] - m) * r * g1 + be1);
        pk[j >> 1] = (u32)lo | ((u32)hi << 16);
      }
      uint4 ov; ov.x = pk[0]; ov.y = pk[1]; ov.z = pk[2]; ov.w = pk[3];
      *(uint4*)(xs + p * PITCH + c) = ov;
    }
    __syncthreads();
  }

  const int pos = t % POS;
  int osub;
  if constexpr (POS == 64) osub = __builtin_amdgcn_readfirstlane(t >> 6);
  else osub = t / POS;
  constexpr int NSUB = 256 / POS;
  constexpr int OPG = NSUB * 8;
  const u16* xrow = xs + pos * PITCH;

#pragma unroll 1
  for (int og = 0; og < COUT / OPG; ++og) {
    const int ob = og * OPG + osub * 8;
    float acc[8];
#pragma unroll
    for (int oi = 0; oi < 8; ++oi) acc[oi] = bf2f(bias[ob + oi]);
#pragma unroll 2
    for (int c = 0; c < CIN; c += 8) {
      uint4 xv = *(const uint4*)(xrow + c);
      float xf[8]; unpack8(xv, xf);
#pragma unroll
      for (int oi = 0; oi < 8; ++oi) {
        uint4 wv = *(const uint4*)(w + (ob + oi) * CIN + c);
        float wf[8]; unpack8(wv, wf);
#pragma unroll
        for (int k = 0; k < 8; ++k) acc[oi] += wf[k] * xf[k];
      }
    }
#pragma unroll
    for (int oi = 0; oi < 8; ++oi) {
      float v = acc[oi];
      if constexpr (SILU) v = v / (1.0f + __expf(-v));
      const size_t gidx = ((size_t)bo2 * COUT + ob + oi) * HW_ + pos0 + pos;
      if constexpr (RES == 2) {
        v += bf2f(((const u16*)resA)[gidx]);
      } else if constexpr (RES == 3) {
        v += ((const float*)resA)[gidx];
      } else if constexpr (RES == 4) {
        const int bl = (bo2 < 2) ? bo2 : bo2 - 2;
        const float* rb = (bo2 < 2) ? (const float*)resA : (const float*)resB;
        v += rb[((size_t)bl * COUT + ob + oi) * HW_ + pos0 + pos];
      }
      if constexpr (OUT_F32) ((float*)out)[gidx] = v;
      else                   ((u16*)out)[gidx] = f2bf(v);
    }
  }
}

// ---------------- attention ----------------
__launch_bounds__(256)
__global__ void attn_kernel(const u16* __restrict__ qb, const u16* __restrict__ kvb,
                            u16* __restrict__ ob) {
  constexpr int PQ = 40;
  constexpr int PV = 264;
  __shared__ __align__(16) u16 qsT[256 * PQ];
  __shared__ __align__(16) u16 ksT[256 * PQ];
  __shared__ __align__(16) u16 vs[32 * PV];
  __shared__ __align__(16) float attnw[4 * 256];
  const int t = threadIdx.x;
  const int h = blockIdx.x, n = blockIdx.y, b = blockIdx.z;
  const size_t qbase = ((size_t)(b * 128 + n * 32)) * HW_ + (size_t)h * W_;
  const size_t kbase = ((size_t)(b * 256 + n * 32)) * HW_ + (size_t)h * W_;
  const size_t vbase = ((size_t)(b * 256 + 128 + n * 32)) * HW_ + (size_t)h * W_;

  for (int d = 0; d < 32; ++d) {
    qsT[t * PQ + d] = qb[qbase + (size_t)d * HW_ + t];
    ksT[t * PQ + d] = kvb[kbase + (size_t)d * HW_ + t];
    vs[d * PV + t] = kvb[vbase + (size_t)d * HW_ + t];
  }
  __syncthreads();

  const int lane = t & 63, wv = t >> 6;
  float* arow = attnw + wv * 256;
  const float scale = 0.17677669529663687f;
  const float renorm = 1.0f / (1.0f + 256.0f * 1e-6f);

  for (int ii = 0; ii < 64; ++ii) {
    const int i = ii * 4 + wv;
    float qf[32];
#pragma unroll
    for (int c8 = 0; c8 < 4; ++c8) {
      uint4 v = *(const uint4*)(&qsT[i * PQ + c8 * 8]);
      unpack8(v, qf + c8 * 8);
    }
    float s[4];
#pragma unroll
    for (int jj = 0; jj < 4; ++jj) {
      const int j = jj * 64 + lane;
      float acc = 0.f;
#pragma unroll
      for (int c8 = 0; c8 < 4; ++c8) {
        uint4 v = *(const uint4*)(&ksT[j * PQ + c8 * 8]);
        float kf[8]; unpack8(v, kf);
#pragma unroll
        for (int k = 0; k < 8; ++k) acc += qf[c8 * 8 + k] * kf[k];
      }
      s[jj] = acc * scale;
    }
    float m = fmaxf(fmaxf(s[0], s[1]), fmaxf(s[2], s[3]));
#pragma unroll
    for (int off = 32; off; off >>= 1) m = fmaxf(m, __shfl_xor(m, off, 64));
    float p[4], sum = 0.f;
#pragma unroll
    for (int jj = 0; jj < 4; ++jj) { p[jj] = __expf(s[jj] - m); sum += p[jj]; }
#pragma unroll
    for (int off = 32; off; off >>= 1) sum += __shfl_xor(sum, off, 64);
    const float inv = 1.0f / sum;
#pragma unroll
    for (int jj = 0; jj < 4; ++jj) arow[jj * 64 + lane] = (p[jj] * inv + 1e-6f) * renorm;

    const int d = lane & 31, jh = lane >> 5;
    float acc = 0.f;
    for (int j0 = jh * 128; j0 < jh * 128 + 128; j0 += 8) {
      float4 a0 = *(const float4*)(&arow[j0]);
      float4 a1 = *(const float4*)(&arow[j0 + 4]);
      uint4 v = *(const uint4*)(&vs[d * PV + j0]);
      float vf[8]; unpack8(v, vf);
      acc += a0.x * vf[0] + a0.y * vf[1] + a0.z * vf[2] + a0.w * vf[3] +
             a1.x * vf[4] + a1.y * vf[5] + a1.z * vf[6] + a1.w * vf[7];
    }
    acc += __shfl_xor(acc, 32, 64);
    if (lane < 32) qsT[i * PQ + d] = f2bf(acc);
  }
  __syncthreads();
  for (int d = 0; d < 32; ++d) ob[qbase + (size_t)d * HW_ + t] = qsT[t * PQ + d];
}

// ---------------- fused depthwise 3/5/7, single batch ----------------
__launch_bounds__(256)
__global__ void dwconv_kernel(const u16* __restrict__ yB,
                              const u16* __restrict__ w3, const u16* __restrict__ b3,
                              const u16* __restrict__ w5, const u16* __restrict__ b5,
                              const u16* __restrict__ w7, const u16* __restrict__ b7,
                              u16* __restrict__ fB) {
  constexpr int LW = 70, LH = 14, LP = 72;
  __shared__ u16 tile[LH * LP];
  __shared__ float wf7[49], wf5[25], wf3[9];
  const int t = threadIdx.x;
  const int c = blockIdx.y;
  const int tw = blockIdx.x & 3, th = blockIdx.x >> 2;
  const int w0 = tw * 64, h0 = th * 8;
  const u16* src = yB + (size_t)c * HW_;

  if (t < 49) wf7[t] = bf2f(w7[c * 49 + t]);
  if (t >= 64 && t < 89) wf5[t - 64] = bf2f(w5[c * 25 + (t - 64)]);
  if (t >= 96 && t < 105) wf3[t - 96] = bf2f(w3[c * 9 + (t - 96)]);

  for (int idx = t; idx < LH * LW; idx += 256) {
    const int r = idx / LW, cc = idx - r * LW;
    const int gh = h0 + r - 3, gw = w0 + cc - 3;
    u16 v = 0;
    if (gh >= 0 && gh < H_ && gw >= 0 && gw < W_) v = src[gh * W_ + gw];
    tile[r * LP + cc] = v;
  }
  __syncthreads();

  const int ww = t & 63, hh = t >> 6;
  const float B3v = bf2f(b3[c]), B5v = bf2f(b5[c]), B7v = bf2f(b7[c]);
#pragma unroll
  for (int pp = 0; pp < 2; ++pp) {
    const int hr = hh + pp * 4;
    float a3 = 0.f, a5 = 0.f, a7 = 0.f;
#pragma unroll
    for (int dy = 0; dy < 7; ++dy) {
#pragma unroll
      for (int dx = 0; dx < 7; ++dx) {
        const float v = bf2f(tile[(hr + dy) * LP + (ww + dx)]);
        a7 += wf7[dy * 7 + dx] * v;
        if (dy >= 1 && dy <= 5 && dx >= 1 && dx <= 5) a5 += wf5[(dy - 1) * 5 + (dx - 1)] * v;
        if (dy >= 2 && dy <= 4 && dx >= 2 && dx <= 4) a3 += wf3[(dy - 2) * 3 + (dx - 2)] * v;
      }
    }
    const size_t o0 = (size_t)c * HW_ + (size_t)(h0 + hr) * W_ + (w0 + ww);
    fB[o0] = f2bf(a3 + B3v);
    fB[o0 + (size_t)256 * HW_] = f2bf(a5 + B5v);
    fB[o0 + (size_t)512 * HW_] = f2bf(a7 + B7v);
  }
}

extern "C" void kernel_launch(void* const* d_in, const int* in_sizes, int n_in,
                              void* d_out, int out_size, void* d_ws, size_t ws_size,
                              hipStream_t stream) {
  (void)out_size; (void)ws_size; (void)n_in;
  char* ws = (char*)d_ws;
  const size_t MB = 1ull << 20;

  // ---- arena: all f32 inputs -> bf16 at ws[0, ~10MB) ----
  u16* arena = (u16*)ws;
  CvtArgs ca;
  u32 off = 0, blk = 0;
  u32 aoff[NT];
  for (int i = 0; i < NT; ++i) {
    ca.src[i] = d_in[i];
    ca.n[i] = (u32)in_sizes[i];
    ca.dst_off[i] = off;
    aoff[i] = off;
    ca.blk_start[i] = blk;
    off += (ca.n[i] + 15u) & ~15u;
    blk += (ca.n[i] + ELEMS_PER_BLK - 1) / ELEMS_PER_BLK;
  }
  const u32 total_blocks = blk;

  const u16* f1c   = arena + aoff[0];
  const u16* f2c   = arena + aoff[1];
  const u16* an_g  = arena + aoff[2];
  const u16* an_b  = arena + aoff[3];
  const u16* anc_g = arena + aoff[4];
  const u16* anc_b = arena + aoff[5];
  const u16* wq    = arena + aoff[6];
  const u16* bq    = arena + aoff[7];
  const u16* wkv   = arena + aoff[8];
  const u16* bkv   = arena + aoff[9];
  const u16* wo    = arena + aoff[10];
  const u16* bo    = arena + aoff[11];
  const u16* fn_g  = arena + aoff[12];
  const u16* fn_b  = arena + aoff[13];
  const u16* w_in  = arena + aoff[14];
  const u16* b_in  = arena + aoff[15];
  const u16* w3    = arena + aoff[16];
  const u16* b3    = arena + aoff[17];
  const u16* w5    = arena + aoff[18];
  const u16* b5    = arena + aoff[19];
  const u16* w7    = arena + aoff[20];
  const u16* b7    = arena + aoff[21];
  const u16* w_pw  = arena + aoff[22];
  const u16* b_pw  = arena + aoff[23];
  const u16* w_out = arena + aoff[24];
  const u16* b_out = arena + aoff[25];

  // ---- overlay plan (peak 144MB) ----
  float* cat1r = (float*)(ws + 24 * MB);   // [24,56)  f32, K4 -> K5,K8
  u16* qb      = (u16*)(ws + 56 * MB);     // [56,72)  K1 -> K3
  u16* kvb     = (u16*)(ws + 72 * MB);     // [72,104) K2 -> K3
  u16* obf     = (u16*)(ws + 104 * MB);    // [104,120) K3 -> K4
  u16* yb      = (u16*)(ws + 56 * MB);     // [56,88)  K5 -> K6,K7
  u16* fbuf_b  = (u16*)(ws + 88 * MB);     // [88,112) per-batch
  u16* y2b     = (u16*)(ws + 112 * MB);    // [112,144) K7 -> K8
  float* outp  = (float*)d_out;

  dim3 blk256(256);
  convert_all<<<total_blocks, 256, 0, stream>>>(ca, arena);

  // K1: q = wq @ LN(cat1; an)
  gemm1x1<128, 128, 64, true, false, false, 0, false>
      <<<dim3(HW_ / 64, 4), blk256, 0, stream>>>(f1c, f2c, wq, bq, an_g, an_b, 1e-6f,
                                                 nullptr, nullptr, qb, 0);
  // K2: kv = wkv @ LN(cat2; anc)
  gemm1x1<128, 256, 64, true, false, false, 0, false>
      <<<dim3(HW_ / 64, 4), blk256, 0, stream>>>(f2c, f1c, wkv, bkv, anc_g, anc_b, 1e-6f,
                                                 nullptr, nullptr, kvb, 0);
  // K3: attention
  attn_kernel<<<dim3(64, 4, 4), blk256, 0, stream>>>(qb, kvb, obf);
  // K4: cat1r = wo @ o + bo + cat1(f32 originals)
  gemm1x1<128, 128, 64, false, false, false, 4, true>
      <<<dim3(HW_ / 64, 4), blk256, 0, stream>>>(obf, nullptr, wo, bo, nullptr, nullptr, 0.f,
                                                 d_in[0], d_in[1], cat1r, 0);
  // K5: y = silu(w_in @ LN(cat1r; fn))
  gemm1x1<128, 256, 64, true, true, true, 0, false>
      <<<dim3(HW_ / 64, 4), blk256, 0, stream>>>(cat1r, nullptr, w_in, b_in, fn_g, fn_b, 1e-5f,
                                                 nullptr, nullptr, yb, 0);
  // K6/K7 per batch
  for (int b = 0; b < 4; ++b) {
    dwconv_kernel<<<dim3(32, 256), blk256, 0, stream>>>(yb + (size_t)b * 256 * HW_,
                                                        w3, b3, w5, b5, w7, b7, fbuf_b);
    gemm1x1<768, 256, 32, false, true, false, 2, false>
        <<<dim3(HW_ / 32, 1), blk256, 0, stream>>>(fbuf_b, nullptr, w_pw, b_pw,
                                                   nullptr, nullptr, 0.f,
                                                   yb, nullptr, y2b, b);
  }
  // K8: out(f32) = cat1r + w_out @ y2 + b_out
  gemm1x1<256, 128, 64, false, false, false, 3, true>
      <<<dim3(HW_ / 64, 4), blk256, 0, stream>>>(y2b, nullptr, w_out, b_out,
                                                 nullptr, nullptr, 0.f,
                                                 cat1r, nullptr, outp, 0);
}

// Round 4
// 1012.241 us; speedup vs baseline: 2.3934x; 2.3934x over previous
//
#include <hip/hip_runtime.h>

typedef unsigned short u16;
typedef unsigned int u32;

constexpr int H_ = 64;
constexpr int W_ = 256;
constexpr int HW_ = H_ * W_;

typedef __bf16 bf16x8 __attribute__((ext_vector_type(8)));
typedef float f32x4 __attribute__((ext_vector_type(4)));

__device__ __forceinline__ float bf2f(u16 v) { return __uint_as_float(((u32)v) << 16); }
__device__ __forceinline__ u16 f2bf(float f) {
  u32 x = __float_as_uint(f);
  u32 r = (x + 0x7fffu + ((x >> 16) & 1u)) >> 16;
  return (u16)r;
}
__device__ __forceinline__ float lo2f(u32 p) { return __uint_as_float(p << 16); }
__device__ __forceinline__ float hi2f(u32 p) { return __uint_as_float(p & 0xffff0000u); }
__device__ __forceinline__ void unpack8(uint4 v, float* f) {
  f[0] = lo2f(v.x); f[1] = hi2f(v.x);
  f[2] = lo2f(v.y); f[3] = hi2f(v.y);
  f[4] = lo2f(v.z); f[5] = hi2f(v.z);
  f[6] = lo2f(v.w); f[7] = hi2f(v.w);
}
__device__ __forceinline__ bf16x8 as_bf16x8(uint4 v) {
  union { uint4 u; bf16x8 b; } x; x.u = v; return x.b;
}

// ---------------- normalize all f32 inputs to a bf16 arena ----------------
constexpr int NT = 26;
constexpr int ELEMS_PER_BLK = 4096;
struct CvtArgs {
  const void* src[NT];
  u32 dst_off[NT];
  u32 n[NT];
  u32 blk_start[NT];
};

__global__ void convert_all(CvtArgs a, u16* __restrict__ dst) {
  const u32 bid = blockIdx.x;
  int ti = 0;
#pragma unroll
  for (int k = 1; k < NT; ++k) if (a.blk_start[k] <= bid) ti = k;
  const u32 e0 = (bid - a.blk_start[ti]) * ELEMS_PER_BLK;
  const u32 n = a.n[ti];
  u32 hi = e0 + ELEMS_PER_BLK; if (hi > n) hi = n;
  const float* sp = (const float*)a.src[ti];
  u16* d = dst + a.dst_off[ti];
  for (u32 i = e0 + threadIdx.x; i < hi; i += 256) d[i] = f2bf(sp[i]);
}

// ---------------- MFMA 1x1-conv GEMM, POS=64 ----------------
// out[b,o,p] = act(sum_c w[o,c]*x[b,c,p] + bias[o]) (+res)
// RES: 0 none, 2 bf16 single, 3 f32 single, 4 f32 dual (cat batch)
// 4 waves split COUT; each wave: MT=COUT/64 M-tiles x 4 N-tiles of 16x16,
// K via mfma_f32_16x16x32_bf16. A=W rows from global (16B/lane),
// B=X from LDS ds_read_b128. C/D: col(pos)=lane&15, row(o)=(lane>>4)*4+r.
template <int CIN, int COUT, bool LN, bool SILU, bool IN_F32, int RES, bool OUT_F32>
__launch_bounds__(256)
__global__ void gemm1x1_mfma(const void* __restrict__ xA, const void* __restrict__ xB,
                             const u16* __restrict__ w, const u16* __restrict__ bias,
                             const u16* __restrict__ lng, const u16* __restrict__ lnb,
                             float lneps,
                             const void* __restrict__ resA, const void* __restrict__ resB,
                             void* __restrict__ out, int b_off) {
  static_assert(!LN || CIN == 128, "LN path assumes CIN=128");
  constexpr int POS = 64;
  constexpr int PITCH = CIN + 8;     // u16 elems; (PITCH*2)%16==0, 4-bank stagger
  constexpr int MT = COUT / 64;      // M-tiles per wave
  __shared__ __align__(16) u16 xs[POS * PITCH];
  const int t = threadIdx.x;
  const int b = blockIdx.y;
  const int bo2 = b + b_off;
  const int pos0 = blockIdx.x * POS;

  const u16* xb16 = nullptr;
  const float* xf32 = nullptr;
  if constexpr (IN_F32) {
    xf32 = ((const float*)xA) + (size_t)b * CIN * HW_;
  } else {
    const u16* basep = (const u16*)((xB != nullptr && b >= 2) ? xB : xA);
    const int bb = (xB != nullptr) ? ((b < 2) ? b : b - 2) : b;
    xb16 = basep + (size_t)bb * CIN * HW_;
  }

  for (int idx = t; idx < CIN * POS; idx += 256) {
    int c = idx / POS, p = idx % POS;
    u16 v;
    if constexpr (IN_F32) v = f2bf(xf32[(size_t)c * HW_ + pos0 + p]);
    else                  v = xb16[(size_t)c * HW_ + pos0 + p];
    xs[p * PITCH + c] = v;
  }
  __syncthreads();

  if constexpr (LN) {
    __shared__ float red1[256], red2[256], stm[64], str[64];
    const int p = t & 63, part = t >> 6;
    float s = 0.f, sq = 0.f;
#pragma unroll
    for (int k = 0; k < 32; k += 8) {
      uint4 v = *(const uint4*)(xs + p * PITCH + part * 32 + k);
      float f[8]; unpack8(v, f);
#pragma unroll
      for (int j = 0; j < 8; ++j) { s += f[j]; sq += f[j] * f[j]; }
    }
    red1[part * 64 + p] = s; red2[part * 64 + p] = sq;
    __syncthreads();
    if (t < 64) {
      float ss = red1[t] + red1[64 + t] + red1[128 + t] + red1[192 + t];
      float qq = red2[t] + red2[64 + t] + red2[128 + t] + red2[192 + t];
      float m = ss * (1.0f / CIN);
      float var = qq * (1.0f / CIN) - m * m;
      var = var < 0.f ? 0.f : var;
      stm[t] = m; str[t] = rsqrtf(var + lneps);
    }
    __syncthreads();
    const float m = stm[p], r = str[p];
#pragma unroll
    for (int k = 0; k < 32; k += 8) {
      const int c = part * 32 + k;
      uint4 v = *(const uint4*)(xs + p * PITCH + c);
      float f[8]; unpack8(v, f);
      u32 pk[4];
#pragma unroll
      for (int j = 0; j < 8; j += 2) {
        float g0 = bf2f(lng[c + j]), be0 = bf2f(lnb[c + j]);
        float g1 = bf2f(lng[c + j + 1]), be1 = bf2f(lnb[c + j + 1]);
        u16 lo = f2bf((f[j] - m) * r * g0 + be0);
        u16 hi = f2bf((f[j + 1] - m) * r * g1 + be1);
        pk[j >> 1] = (u32)lo | ((u32)hi << 16);
      }
      uint4 ov; ov.x = pk[0]; ov.y = pk[1]; ov.z = pk[2]; ov.w = pk[3];
      *(uint4*)(xs + p * PITCH + c) = ov;
    }
    __syncthreads();
  }

  const int lane = t & 63, wv = t >> 6;
  const int lo16 = lane & 15, quad = lane >> 4;
  const int orow0 = wv * MT * 16;           // this wave's first output channel
  const int qrow = quad * 4;                // C/D row base for this lane

  f32x4 acc[MT][4];
#pragma unroll
  for (int mt = 0; mt < MT; ++mt) {
#pragma unroll
    for (int r = 0; r < 4; ++r) {
      const float bv = bf2f(bias[orow0 + mt * 16 + qrow + r]);
#pragma unroll
      for (int nt = 0; nt < 4; ++nt) acc[mt][nt][r] = bv;
    }
  }

  const u16* xsl = xs + lo16 * PITCH + quad * 8;
  const u16* wl = w + (size_t)(orow0 + lo16) * CIN + quad * 8;

#pragma unroll 2
  for (int kc = 0; kc < CIN / 32; ++kc) {
    const int c0 = kc * 32;
    bf16x8 bfr[4];
#pragma unroll
    for (int nt = 0; nt < 4; ++nt)
      bfr[nt] = as_bf16x8(*(const uint4*)(xsl + nt * 16 * PITCH + c0));
#pragma unroll
    for (int mt = 0; mt < MT; ++mt) {
      bf16x8 afr = as_bf16x8(*(const uint4*)(wl + (size_t)mt * 16 * CIN + c0));
#pragma unroll
      for (int nt = 0; nt < 4; ++nt)
        acc[mt][nt] = __builtin_amdgcn_mfma_f32_16x16x32_bf16(afr, bfr[nt], acc[mt][nt], 0, 0, 0);
    }
  }

#pragma unroll
  for (int mt = 0; mt < MT; ++mt) {
#pragma unroll
    for (int nt = 0; nt < 4; ++nt) {
#pragma unroll
      for (int r = 0; r < 4; ++r) {
        const int o = orow0 + mt * 16 + qrow + r;
        const int p = pos0 + nt * 16 + lo16;
        float v = acc[mt][nt][r];
        if constexpr (SILU) v = v / (1.0f + __expf(-v));
        const size_t gidx = ((size_t)bo2 * COUT + o) * HW_ + p;
        if constexpr (RES == 2) {
          v += bf2f(((const u16*)resA)[gidx]);
        } else if constexpr (RES == 3) {
          v += ((const float*)resA)[gidx];
        } else if constexpr (RES == 4) {
          const int bl = (bo2 < 2) ? bo2 : bo2 - 2;
          const float* rb = (bo2 < 2) ? (const float*)resA : (const float*)resB;
          v += rb[((size_t)bl * COUT + o) * HW_ + p];
        }
        if constexpr (OUT_F32) ((float*)out)[gidx] = v;
        else                   ((u16*)out)[gidx] = f2bf(v);
      }
    }
  }
}

// ---------------- attention (unchanged this round) ----------------
__launch_bounds__(256)
__global__ void attn_kernel(const u16* __restrict__ qb, const u16* __restrict__ kvb,
                            u16* __restrict__ ob) {
  constexpr int PQ = 40;
  constexpr int PV = 264;
  __shared__ __align__(16) u16 qsT[256 * PQ];
  __shared__ __align__(16) u16 ksT[256 * PQ];
  __shared__ __align__(16) u16 vs[32 * PV];
  __shared__ __align__(16) float attnw[4 * 256];
  const int t = threadIdx.x;
  const int h = blockIdx.x, n = blockIdx.y, b = blockIdx.z;
  const size_t qbase = ((size_t)(b * 128 + n * 32)) * HW_ + (size_t)h * W_;
  const size_t kbase = ((size_t)(b * 256 + n * 32)) * HW_ + (size_t)h * W_;
  const size_t vbase = ((size_t)(b * 256 + 128 + n * 32)) * HW_ + (size_t)h * W_;

  for (int d = 0; d < 32; ++d) {
    qsT[t * PQ + d] = qb[qbase + (size_t)d * HW_ + t];
    ksT[t * PQ + d] = kvb[kbase + (size_t)d * HW_ + t];
    vs[d * PV + t] = kvb[vbase + (size_t)d * HW_ + t];
  }
  __syncthreads();

  const int lane = t & 63, wv = t >> 6;
  float* arow = attnw + wv * 256;
  const float scale = 0.17677669529663687f;
  const float renorm = 1.0f / (1.0f + 256.0f * 1e-6f);

  for (int ii = 0; ii < 64; ++ii) {
    const int i = ii * 4 + wv;
    float qf[32];
#pragma unroll
    for (int c8 = 0; c8 < 4; ++c8) {
      uint4 v = *(const uint4*)(&qsT[i * PQ + c8 * 8]);
      unpack8(v, qf + c8 * 8);
    }
    float s[4];
#pragma unroll
    for (int jj = 0; jj < 4; ++jj) {
      const int j = jj * 64 + lane;
      float acc = 0.f;
#pragma unroll
      for (int c8 = 0; c8 < 4; ++c8) {
        uint4 v = *(const uint4*)(&ksT[j * PQ + c8 * 8]);
        float kf[8]; unpack8(v, kf);
#pragma unroll
        for (int k = 0; k < 8; ++k) acc += qf[c8 * 8 + k] * kf[k];
      }
      s[jj] = acc * scale;
    }
    float m = fmaxf(fmaxf(s[0], s[1]), fmaxf(s[2], s[3]));
#pragma unroll
    for (int off = 32; off; off >>= 1) m = fmaxf(m, __shfl_xor(m, off, 64));
    float p[4], sum = 0.f;
#pragma unroll
    for (int jj = 0; jj < 4; ++jj) { p[jj] = __expf(s[jj] - m); sum += p[jj]; }
#pragma unroll
    for (int off = 32; off; off >>= 1) sum += __shfl_xor(sum, off, 64);
    const float inv = 1.0f / sum;
#pragma unroll
    for (int jj = 0; jj < 4; ++jj) arow[jj * 64 + lane] = (p[jj] * inv + 1e-6f) * renorm;

    const int d = lane & 31, jh = lane >> 5;
    float acc = 0.f;
    for (int j0 = jh * 128; j0 < jh * 128 + 128; j0 += 8) {
      float4 a0 = *(const float4*)(&arow[j0]);
      float4 a1 = *(const float4*)(&arow[j0 + 4]);
      uint4 v = *(const uint4*)(&vs[d * PV + j0]);
      float vf[8]; unpack8(v, vf);
      acc += a0.x * vf[0] + a0.y * vf[1] + a0.z * vf[2] + a0.w * vf[3] +
             a1.x * vf[4] + a1.y * vf[5] + a1.z * vf[6] + a1.w * vf[7];
    }
    acc += __shfl_xor(acc, 32, 64);
    if (lane < 32) qsT[i * PQ + d] = f2bf(acc);
  }
  __syncthreads();
  for (int d = 0; d < 32; ++d) ob[qbase + (size_t)d * HW_ + t] = qsT[t * PQ + d];
}

// ---------------- fused depthwise 3/5/7, single batch ----------------
__launch_bounds__(256)
__global__ void dwconv_kernel(const u16* __restrict__ yB,
                              const u16* __restrict__ w3, const u16* __restrict__ b3,
                              const u16* __restrict__ w5, const u16* __restrict__ b5,
                              const u16* __restrict__ w7, const u16* __restrict__ b7,
                              u16* __restrict__ fB) {
  constexpr int LW = 70, LH = 14, LP = 72;
  __shared__ u16 tile[LH * LP];
  __shared__ float wf7[49], wf5[25], wf3[9];
  const int t = threadIdx.x;
  const int c = blockIdx.y;
  const int tw = blockIdx.x & 3, th = blockIdx.x >> 2;
  const int w0 = tw * 64, h0 = th * 8;
  const u16* src = yB + (size_t)c * HW_;

  if (t < 49) wf7[t] = bf2f(w7[c * 49 + t]);
  if (t >= 64 && t < 89) wf5[t - 64] = bf2f(w5[c * 25 + (t - 64)]);
  if (t >= 96 && t < 105) wf3[t - 96] = bf2f(w3[c * 9 + (t - 96)]);

  for (int idx = t; idx < LH * LW; idx += 256) {
    const int r = idx / LW, cc = idx - r * LW;
    const int gh = h0 + r - 3, gw = w0 + cc - 3;
    u16 v = 0;
    if (gh >= 0 && gh < H_ && gw >= 0 && gw < W_) v = src[gh * W_ + gw];
    tile[r * LP + cc] = v;
  }
  __syncthreads();

  const int ww = t & 63, hh = t >> 6;
  const float B3v = bf2f(b3[c]), B5v = bf2f(b5[c]), B7v = bf2f(b7[c]);
#pragma unroll
  for (int pp = 0; pp < 2; ++pp) {
    const int hr = hh + pp * 4;
    float a3 = 0.f, a5 = 0.f, a7 = 0.f;
#pragma unroll
    for (int dy = 0; dy < 7; ++dy) {
#pragma unroll
      for (int dx = 0; dx < 7; ++dx) {
        const float v = bf2f(tile[(hr + dy) * LP + (ww + dx)]);
        a7 += wf7[dy * 7 + dx] * v;
        if (dy >= 1 && dy <= 5 && dx >= 1 && dx <= 5) a5 += wf5[(dy - 1) * 5 + (dx - 1)] * v;
        if (dy >= 2 && dy <= 4 && dx >= 2 && dx <= 4) a3 += wf3[(dy - 2) * 3 + (dx - 2)] * v;
      }
    }
    const size_t o0 = (size_t)c * HW_ + (size_t)(h0 + hr) * W_ + (w0 + ww);
    fB[o0] = f2bf(a3 + B3v);
    fB[o0 + (size_t)256 * HW_] = f2bf(a5 + B5v);
    fB[o0 + (size_t)512 * HW_] = f2bf(a7 + B7v);
  }
}

extern "C" void kernel_launch(void* const* d_in, const int* in_sizes, int n_in,
                              void* d_out, int out_size, void* d_ws, size_t ws_size,
                              hipStream_t stream) {
  (void)out_size; (void)ws_size; (void)n_in;
  char* ws = (char*)d_ws;
  const size_t MB = 1ull << 20;

  u16* arena = (u16*)ws;
  CvtArgs ca;
  u32 off = 0, blk = 0;
  u32 aoff[NT];
  for (int i = 0; i < NT; ++i) {
    ca.src[i] = d_in[i];
    ca.n[i] = (u32)in_sizes[i];
    ca.dst_off[i] = off;
    aoff[i] = off;
    ca.blk_start[i] = blk;
    off += (ca.n[i] + 15u) & ~15u;
    blk += (ca.n[i] + ELEMS_PER_BLK - 1) / ELEMS_PER_BLK;
  }
  const u32 total_blocks = blk;

  const u16* f1c   = arena + aoff[0];
  const u16* f2c   = arena + aoff[1];
  const u16* an_g  = arena + aoff[2];
  const u16* an_b  = arena + aoff[3];
  const u16* anc_g = arena + aoff[4];
  const u16* anc_b = arena + aoff[5];
  const u16* wq    = arena + aoff[6];
  const u16* bq    = arena + aoff[7];
  const u16* wkv   = arena + aoff[8];
  const u16* bkv   = arena + aoff[9];
  const u16* wo    = arena + aoff[10];
  const u16* bo    = arena + aoff[11];
  const u16* fn_g  = arena + aoff[12];
  const u16* fn_b  = arena + aoff[13];
  const u16* w_in  = arena + aoff[14];
  const u16* b_in  = arena + aoff[15];
  const u16* w3    = arena + aoff[16];
  const u16* b3    = arena + aoff[17];
  const u16* w5    = arena + aoff[18];
  const u16* b5    = arena + aoff[19];
  const u16* w7    = arena + aoff[20];
  const u16* b7    = arena + aoff[21];
  const u16* w_pw  = arena + aoff[22];
  const u16* b_pw  = arena + aoff[23];
  const u16* w_out = arena + aoff[24];
  const u16* b_out = arena + aoff[25];

  float* cat1r = (float*)(ws + 24 * MB);   // [24,56)  f32, K4 -> K5,K8
  u16* qb      = (u16*)(ws + 56 * MB);     // [56,72)  K1 -> K3
  u16* kvb     = (u16*)(ws + 72 * MB);     // [72,104) K2 -> K3
  u16* obf     = (u16*)(ws + 104 * MB);    // [104,120) K3 -> K4
  u16* yb      = (u16*)(ws + 56 * MB);     // [56,88)  K5 -> K6,K7
  u16* fbuf_b  = (u16*)(ws + 88 * MB);     // [88,112) per-batch
  u16* y2b     = (u16*)(ws + 112 * MB);    // [112,144) K7 -> K8
  float* outp  = (float*)d_out;

  dim3 blk256(256);
  convert_all<<<total_blocks, 256, 0, stream>>>(ca, arena);

  // K1: q = wq @ LN(cat1; an)
  gemm1x1_mfma<128, 128, true, false, false, 0, false>
      <<<dim3(HW_ / 64, 4), blk256, 0, stream>>>(f1c, f2c, wq, bq, an_g, an_b, 1e-6f,
                                                 nullptr, nullptr, qb, 0);
  // K2: kv = wkv @ LN(cat2; anc)
  gemm1x1_mfma<128, 256, true, false, false, 0, false>
      <<<dim3(HW_ / 64, 4), blk256, 0, stream>>>(f2c, f1c, wkv, bkv, anc_g, anc_b, 1e-6f,
                                                 nullptr, nullptr, kvb, 0);
  // K3: attention
  attn_kernel<<<dim3(64, 4, 4), blk256, 0, stream>>>(qb, kvb, obf);
  // K4: cat1r = wo @ o + bo + cat1(f32 originals)
  gemm1x1_mfma<128, 128, false, false, false, 4, true>
      <<<dim3(HW_ / 64, 4), blk256, 0, stream>>>(obf, nullptr, wo, bo, nullptr, nullptr, 0.f,
                                                 d_in[0], d_in[1], cat1r, 0);
  // K5: y = silu(w_in @ LN(cat1r; fn))
  gemm1x1_mfma<128, 256, true, true, true, 0, false>
      <<<dim3(HW_ / 64, 4), blk256, 0, stream>>>(cat1r, nullptr, w_in, b_in, fn_g, fn_b, 1e-5f,
                                                 nullptr, nullptr, yb, 0);
  // K6/K7 per batch
  for (int b = 0; b < 4; ++b) {
    dwconv_kernel<<<dim3(32, 256), blk256, 0, stream>>>(yb + (size_t)b * 256 * HW_,
                                                        w3, b3, w5, b5, w7, b7, fbuf_b);
    gemm1x1_mfma<768, 256, false, true, false, 2, false>
        <<<dim3(HW_ / 64, 1), blk256, 0, stream>>>(fbuf_b, nullptr, w_pw, b_pw,
                                                   nullptr, nullptr, 0.f,
                                                   yb, nullptr, y2b, b);
  }
  // K8: out(f32) = cat1r + w_out @ y2 + b_out
  gemm1x1_mfma<256, 128, false, false, false, 3, true>
      <<<dim3(HW_ / 64, 4), blk256, 0, stream>>>(y2b, nullptr, w_out, b_out,
                                                 nullptr, nullptr, 0.f,
                                                 cat1r, nullptr, outp, 0);
}

// Round 5
// 712.436 us; speedup vs baseline: 3.4006x; 1.4208x over previous
//
#include <hip/hip_runtime.h>

typedef unsigned short u16;
typedef unsigned int u32;

constexpr int H_ = 64;
constexpr int W_ = 256;
constexpr int HW_ = H_ * W_;

typedef __bf16 bf16x8 __attribute__((ext_vector_type(8)));
typedef float f32x4 __attribute__((ext_vector_type(4)));

__device__ __forceinline__ float bf2f(u16 v) { return __uint_as_float(((u32)v) << 16); }
__device__ __forceinline__ u16 f2bf(float f) {
  u32 x = __float_as_uint(f);
  u32 r = (x + 0x7fffu + ((x >> 16) & 1u)) >> 16;
  return (u16)r;
}
__device__ __forceinline__ float lo2f(u32 p) { return __uint_as_float(p << 16); }
__device__ __forceinline__ float hi2f(u32 p) { return __uint_as_float(p & 0xffff0000u); }
__device__ __forceinline__ void unpack8(uint4 v, float* f) {
  f[0] = lo2f(v.x); f[1] = hi2f(v.x);
  f[2] = lo2f(v.y); f[3] = hi2f(v.y);
  f[4] = lo2f(v.z); f[5] = hi2f(v.z);
  f[6] = lo2f(v.w); f[7] = hi2f(v.w);
}
__device__ __forceinline__ bf16x8 as_bf16x8(uint4 v) {
  union { uint4 u; bf16x8 b; } x; x.u = v; return x.b;
}

// ---------------- normalize all f32 inputs to a bf16 arena ----------------
constexpr int NT = 26;
constexpr int ELEMS_PER_BLK = 4096;
struct CvtArgs {
  const void* src[NT];
  u32 dst_off[NT];
  u32 n[NT];
  u32 blk_start[NT];
};

__global__ void convert_all(CvtArgs a, u16* __restrict__ dst) {
  const u32 bid = blockIdx.x;
  int ti = 0;
#pragma unroll
  for (int k = 1; k < NT; ++k) if (a.blk_start[k] <= bid) ti = k;
  const u32 e0 = (bid - a.blk_start[ti]) * ELEMS_PER_BLK;
  const u32 n = a.n[ti];
  u32 hi = e0 + ELEMS_PER_BLK; if (hi > n) hi = n;
  const float* sp = (const float*)a.src[ti];
  u16* d = dst + a.dst_off[ti];
  for (u32 i = e0 + threadIdx.x; i < hi; i += 256) d[i] = f2bf(sp[i]);
}

// ---------------- MFMA 1x1-conv GEMM, POS=64 ----------------
// out[b,o,p] = act(sum_c w[o,c]*x[b,c,p] + bias[o]) (+res)
// RES: 0 none, 2 bf16 single, 3 f32 single, 4 f32 dual (cat batch)
// NOG: COUT split across blockIdx.z (occupancy for big-CIN GEMMs).
template <int CIN, int COUT, int NOG, bool LN, bool SILU, bool IN_F32, int RES, bool OUT_F32>
__launch_bounds__(256)
__global__ void gemm1x1_mfma(const void* __restrict__ xA, const void* __restrict__ xB,
                             const u16* __restrict__ w, const u16* __restrict__ bias,
                             const u16* __restrict__ lng, const u16* __restrict__ lnb,
                             float lneps,
                             const void* __restrict__ resA, const void* __restrict__ resB,
                             void* __restrict__ out, int b_off) {
  static_assert(!LN || CIN == 128, "LN path assumes CIN=128");
  constexpr int POS = 64;
  constexpr int PITCH = CIN + 8;
  constexpr int MT = COUT / NOG / 64;   // M-tiles per wave
  __shared__ __align__(16) u16 xs[POS * PITCH];
  const int t = threadIdx.x;
  const int b = blockIdx.y;
  const int bo2 = b + b_off;
  const int pos0 = blockIdx.x * POS;
  const int og0 = blockIdx.z * (COUT / NOG);

  const u16* xb16 = nullptr;
  const float* xf32 = nullptr;
  if constexpr (IN_F32) {
    xf32 = ((const float*)xA) + (size_t)b * CIN * HW_;
  } else {
    const u16* basep = (const u16*)((xB != nullptr && b >= 2) ? xB : xA);
    const int bb = (xB != nullptr) ? ((b < 2) ? b : b - 2) : b;
    xb16 = basep + (size_t)bb * CIN * HW_;
  }

  for (int idx = t; idx < CIN * POS; idx += 256) {
    int c = idx / POS, p = idx % POS;
    u16 v;
    if constexpr (IN_F32) v = f2bf(xf32[(size_t)c * HW_ + pos0 + p]);
    else                  v = xb16[(size_t)c * HW_ + pos0 + p];
    xs[p * PITCH + c] = v;
  }
  __syncthreads();

  if constexpr (LN) {
    __shared__ float red1[256], red2[256], stm[64], str[64];
    const int p = t & 63, part = t >> 6;
    float s = 0.f, sq = 0.f;
#pragma unroll
    for (int k = 0; k < 32; k += 8) {
      uint4 v = *(const uint4*)(xs + p * PITCH + part * 32 + k);
      float f[8]; unpack8(v, f);
#pragma unroll
      for (int j = 0; j < 8; ++j) { s += f[j]; sq += f[j] * f[j]; }
    }
    red1[part * 64 + p] = s; red2[part * 64 + p] = sq;
    __syncthreads();
    if (t < 64) {
      float ss = red1[t] + red1[64 + t] + red1[128 + t] + red1[192 + t];
      float qq = red2[t] + red2[64 + t] + red2[128 + t] + red2[192 + t];
      float m = ss * (1.0f / CIN);
      float var = qq * (1.0f / CIN) - m * m;
      var = var < 0.f ? 0.f : var;
      stm[t] = m; str[t] = rsqrtf(var + lneps);
    }
    __syncthreads();
    const float m = stm[p], r = str[p];
#pragma unroll
    for (int k = 0; k < 32; k += 8) {
      const int c = part * 32 + k;
      uint4 v = *(const uint4*)(xs + p * PITCH + c);
      float f[8]; unpack8(v, f);
      u32 pk[4];
#pragma unroll
      for (int j = 0; j < 8; j += 2) {
        float g0 = bf2f(lng[c + j]), be0 = bf2f(lnb[c + j]);
        float g1 = bf2f(lng[c + j + 1]), be1 = bf2f(lnb[c + j + 1]);
        u16 lo = f2bf((f[j] - m) * r * g0 + be0);
        u16 hi = f2bf((f[j + 1] - m) * r * g1 + be1);
        pk[j >> 1] = (u32)lo | ((u32)hi << 16);
      }
      uint4 ov; ov.x = pk[0]; ov.y = pk[1]; ov.z = pk[2]; ov.w = pk[3];
      *(uint4*)(xs + p * PITCH + c) = ov;
    }
    __syncthreads();
  }

  const int lane = t & 63, wv = t >> 6;
  const int lo16 = lane & 15, quad = lane >> 4;
  const int orow0 = og0 + wv * MT * 16;
  const int qrow = quad * 4;

  f32x4 acc[MT][4];
#pragma unroll
  for (int mt = 0; mt < MT; ++mt) {
#pragma unroll
    for (int r = 0; r < 4; ++r) {
      const float bv = bf2f(bias[orow0 + mt * 16 + qrow + r]);
#pragma unroll
      for (int nt = 0; nt < 4; ++nt) acc[mt][nt][r] = bv;
    }
  }

  const u16* xsl = xs + lo16 * PITCH + quad * 8;
  const u16* wl = w + (size_t)(orow0 + lo16) * CIN + quad * 8;

#pragma unroll 2
  for (int kc = 0; kc < CIN / 32; ++kc) {
    const int c0 = kc * 32;
    bf16x8 bfr[4];
#pragma unroll
    for (int nt = 0; nt < 4; ++nt)
      bfr[nt] = as_bf16x8(*(const uint4*)(xsl + nt * 16 * PITCH + c0));
#pragma unroll
    for (int mt = 0; mt < MT; ++mt) {
      bf16x8 afr = as_bf16x8(*(const uint4*)(wl + (size_t)mt * 16 * CIN + c0));
#pragma unroll
      for (int nt = 0; nt < 4; ++nt)
        acc[mt][nt] = __builtin_amdgcn_mfma_f32_16x16x32_bf16(afr, bfr[nt], acc[mt][nt], 0, 0, 0);
    }
  }

#pragma unroll
  for (int mt = 0; mt < MT; ++mt) {
#pragma unroll
    for (int nt = 0; nt < 4; ++nt) {
#pragma unroll
      for (int r = 0; r < 4; ++r) {
        const int o = orow0 + mt * 16 + qrow + r;
        const int p = pos0 + nt * 16 + lo16;
        float v = acc[mt][nt][r];
        if constexpr (SILU) v = v / (1.0f + __expf(-v));
        const size_t gidx = ((size_t)bo2 * COUT + o) * HW_ + p;
        if constexpr (RES == 2) {
          v += bf2f(((const u16*)resA)[gidx]);
        } else if constexpr (RES == 3) {
          v += ((const float*)resA)[gidx];
        } else if constexpr (RES == 4) {
          const int bl = (bo2 < 2) ? bo2 : bo2 - 2;
          const float* rb = (bo2 < 2) ? (const float*)resA : (const float*)resB;
          v += rb[((size_t)bl * COUT + o) * HW_ + p];
        }
        if constexpr (OUT_F32) ((float*)out)[gidx] = v;
        else                   ((u16*)out)[gidx] = f2bf(v);
      }
    }
  }
}

// ---------------- MFMA attention ----------------
// One block per (b,n,h). qT[i][d], kT[j][d] pitch 40; vT[d][j] pitch 264;
// P (bf16) per-wave 16x256 pitch 264. Wave wv owns i-tile ii*64+wv*16.
// QK: A=qT row tile, B=kT row tiles, D: col=j, row=i. Softmax in regs
// (quad holds rows quad*4+r; shfl_xor 1/2/4/8 reduces across j-lanes).
// P -> LDS (C->A transform) -> PV: A=P, B=vT, D: col=d, row=i.
__launch_bounds__(256)
__global__ void attn_mfma(const u16* __restrict__ qb, const u16* __restrict__ kvb,
                          u16* __restrict__ ob) {
  constexpr int PA = 40;    // qT/kT pitch (u16): 80B rows, b128-aligned
  constexpr int PJ = 264;   // vT/P pitch (u16): 528B rows, b128-aligned
  __shared__ __align__(16) u16 qT[256 * PA];   // rows reused for O after consumption
  __shared__ __align__(16) u16 kT[256 * PA];
  __shared__ __align__(16) u16 vT[32 * PJ];
  __shared__ __align__(16) u16 Pl[4 * 16 * PJ];
  const int t = threadIdx.x;
  const int h = blockIdx.x, n = blockIdx.y, b = blockIdx.z;
  const size_t qbase = ((size_t)(b * 128 + n * 32)) * HW_ + (size_t)h * W_;
  const size_t kbase = ((size_t)(b * 256 + n * 32)) * HW_ + (size_t)h * W_;
  const size_t vbase = ((size_t)(b * 256 + 128 + n * 32)) * HW_ + (size_t)h * W_;

  // stage qT/kT: thread t owns position t; pack 8 d's -> one b128 write
#pragma unroll
  for (int d8 = 0; d8 < 4; ++d8) {
    u32 pk[4];
#pragma unroll
    for (int j = 0; j < 4; ++j) {
      u32 lo = qb[qbase + (size_t)(d8 * 8 + 2 * j) * HW_ + t];
      u32 hi = qb[qbase + (size_t)(d8 * 8 + 2 * j + 1) * HW_ + t];
      pk[j] = lo | (hi << 16);
    }
    *(uint4*)(qT + t * PA + d8 * 8) = make_uint4(pk[0], pk[1], pk[2], pk[3]);
#pragma unroll
    for (int j = 0; j < 4; ++j) {
      u32 lo = kvb[kbase + (size_t)(d8 * 8 + 2 * j) * HW_ + t];
      u32 hi = kvb[kbase + (size_t)(d8 * 8 + 2 * j + 1) * HW_ + t];
      pk[j] = lo | (hi << 16);
    }
    *(uint4*)(kT + t * PA + d8 * 8) = make_uint4(pk[0], pk[1], pk[2], pk[3]);
  }
  // stage vT[d][j]: u32 (2 positions) per op, coalesced global + contiguous LDS
#pragma unroll
  for (int k = 0; k < 16; ++k) {
    const int idx = k * 256 + t;          // (d, p2): d = idx/128, p2 = (idx%128)*2
    const int d = idx >> 7, p2 = (idx & 127) * 2;
    u32 v = *(const u32*)(kvb + vbase + (size_t)d * HW_ + p2);
    *(u32*)(vT + d * PJ + p2) = v;
  }
  __syncthreads();

  const int lane = t & 63, wv = t >> 6;
  const int lo16 = lane & 15, quad = lane >> 4;
  const float scale = 0.17677669529663687f;  // 32^-0.5
  const float renorm = 1.0f / (1.0f + 256.0f * 1e-6f);
  u16* Pw = Pl + wv * 16 * PJ;

  for (int ii = 0; ii < 4; ++ii) {
    const int i0 = ii * 64 + wv * 16;
    // ---- QK^T ----
    bf16x8 qa = as_bf16x8(*(const uint4*)(qT + (i0 + lo16) * PA + quad * 8));
    f32x4 s[16];
#pragma unroll
    for (int jt = 0; jt < 16; ++jt) {
      bf16x8 kb = as_bf16x8(*(const uint4*)(kT + (jt * 16 + lo16) * PA + quad * 8));
      f32x4 z = {0.f, 0.f, 0.f, 0.f};
      s[jt] = __builtin_amdgcn_mfma_f32_16x16x32_bf16(qa, kb, z, 0, 0, 0);
    }
    // ---- softmax (+eps renorm) ----
#pragma unroll
    for (int r = 0; r < 4; ++r) {
      float m = s[0][r] ;
#pragma unroll
      for (int jt = 1; jt < 16; ++jt) m = fmaxf(m, s[jt][r]);
      m *= scale;
#pragma unroll
      for (int off = 1; off <= 8; off <<= 1) m = fmaxf(m, __shfl_xor(m, off, 64));
      float sum = 0.f;
#pragma unroll
      for (int jt = 0; jt < 16; ++jt) {
        float e = __expf(s[jt][r] * scale - m);
        s[jt][r] = e; sum += e;
      }
#pragma unroll
      for (int off = 1; off <= 8; off <<= 1) sum += __shfl_xor(sum, off, 64);
      const float inv = 1.0f / sum;
#pragma unroll
      for (int jt = 0; jt < 16; ++jt)
        Pw[(quad * 4 + r) * PJ + jt * 16 + lo16] = f2bf((s[jt][r] * inv + 1e-6f) * renorm);
    }
    __syncthreads();   // P visible (own-wave lgkm drain; uniform across waves)
    // ---- PV ----
    f32x4 o0 = {0.f, 0.f, 0.f, 0.f}, o1 = {0.f, 0.f, 0.f, 0.f};
#pragma unroll
    for (int kt = 0; kt < 8; ++kt) {
      bf16x8 pa = as_bf16x8(*(const uint4*)(Pw + lo16 * PJ + kt * 32 + quad * 8));
      bf16x8 v0 = as_bf16x8(*(const uint4*)(vT + lo16 * PJ + kt * 32 + quad * 8));
      bf16x8 v1 = as_bf16x8(*(const uint4*)(vT + (16 + lo16) * PJ + kt * 32 + quad * 8));
      o0 = __builtin_amdgcn_mfma_f32_16x16x32_bf16(pa, v0, o0, 0, 0, 0);
      o1 = __builtin_amdgcn_mfma_f32_16x16x32_bf16(pa, v1, o1, 0, 0, 0);
    }
    // O -> qT rows (consumed at iter start): [i][d]
#pragma unroll
    for (int r = 0; r < 4; ++r) {
      qT[(i0 + quad * 4 + r) * PA + lo16] = f2bf(o0[r]);
      qT[(i0 + quad * 4 + r) * PA + 16 + lo16] = f2bf(o1[r]);
    }
    __syncthreads();
  }
  // coalesced store
  for (int d = 0; d < 32; ++d) ob[qbase + (size_t)d * HW_ + t] = qT[t * PA + d];
}

// ---------------- fused depthwise 3/5/7, single batch ----------------
__launch_bounds__(256)
__global__ void dwconv_kernel(const u16* __restrict__ yB,
                              const u16* __restrict__ w3, const u16* __restrict__ b3,
                              const u16* __restrict__ w5, const u16* __restrict__ b5,
                              const u16* __restrict__ w7, const u16* __restrict__ b7,
                              u16* __restrict__ fB) {
  constexpr int LW = 70, LH = 14, LP = 72;
  __shared__ u16 tile[LH * LP];
  __shared__ float wf7[49], wf5[25], wf3[9];
  const int t = threadIdx.x;
  const int c = blockIdx.y;
  const int tw = blockIdx.x & 3, th = blockIdx.x >> 2;
  const int w0 = tw * 64, h0 = th * 8;
  const u16* src = yB + (size_t)c * HW_;

  if (t < 49) wf7[t] = bf2f(w7[c * 49 + t]);
  if (t >= 64 && t < 89) wf5[t - 64] = bf2f(w5[c * 25 + (t - 64)]);
  if (t >= 96 && t < 105) wf3[t - 96] = bf2f(w3[c * 9 + (t - 96)]);

  for (int idx = t; idx < LH * LW; idx += 256) {
    const int r = idx / LW, cc = idx - r * LW;
    const int gh = h0 + r - 3, gw = w0 + cc - 3;
    u16 v = 0;
    if (gh >= 0 && gh < H_ && gw >= 0 && gw < W_) v = src[gh * W_ + gw];
    tile[r * LP + cc] = v;
  }
  __syncthreads();

  const int ww = t & 63, hh = t >> 6;
  const float B3v = bf2f(b3[c]), B5v = bf2f(b5[c]), B7v = bf2f(b7[c]);
#pragma unroll
  for (int pp = 0; pp < 2; ++pp) {
    const int hr = hh + pp * 4;
    float a3 = 0.f, a5 = 0.f, a7 = 0.f;
#pragma unroll
    for (int dy = 0; dy < 7; ++dy) {
#pragma unroll
      for (int dx = 0; dx < 7; ++dx) {
        const float v = bf2f(tile[(hr + dy) * LP + (ww + dx)]);
        a7 += wf7[dy * 7 + dx] * v;
        if (dy >= 1 && dy <= 5 && dx >= 1 && dx <= 5) a5 += wf5[(dy - 1) * 5 + (dx - 1)] * v;
        if (dy >= 2 && dy <= 4 && dx >= 2 && dx <= 4) a3 += wf3[(dy - 2) * 3 + (dx - 2)] * v;
      }
    }
    const size_t o0 = (size_t)c * HW_ + (size_t)(h0 + hr) * W_ + (w0 + ww);
    fB[o0] = f2bf(a3 + B3v);
    fB[o0 + (size_t)256 * HW_] = f2bf(a5 + B5v);
    fB[o0 + (size_t)512 * HW_] = f2bf(a7 + B7v);
  }
}

extern "C" void kernel_launch(void* const* d_in, const int* in_sizes, int n_in,
                              void* d_out, int out_size, void* d_ws, size_t ws_size,
                              hipStream_t stream) {
  (void)out_size; (void)ws_size; (void)n_in;
  char* ws = (char*)d_ws;
  const size_t MB = 1ull << 20;

  u16* arena = (u16*)ws;
  CvtArgs ca;
  u32 off = 0, blk = 0;
  u32 aoff[NT];
  for (int i = 0; i < NT; ++i) {
    ca.src[i] = d_in[i];
    ca.n[i] = (u32)in_sizes[i];
    ca.dst_off[i] = off;
    aoff[i] = off;
    ca.blk_start[i] = blk;
    off += (ca.n[i] + 15u) & ~15u;
    blk += (ca.n[i] + ELEMS_PER_BLK - 1) / ELEMS_PER_BLK;
  }
  const u32 total_blocks = blk;

  const u16* f1c   = arena + aoff[0];
  const u16* f2c   = arena + aoff[1];
  const u16* an_g  = arena + aoff[2];
  const u16* an_b  = arena + aoff[3];
  const u16* anc_g = arena + aoff[4];
  const u16* anc_b = arena + aoff[5];
  const u16* wq    = arena + aoff[6];
  const u16* bq    = arena + aoff[7];
  const u16* wkv   = arena + aoff[8];
  const u16* bkv   = arena + aoff[9];
  const u16* wo    = arena + aoff[10];
  const u16* bo    = arena + aoff[11];
  const u16* fn_g  = arena + aoff[12];
  const u16* fn_b  = arena + aoff[13];
  const u16* w_in  = arena + aoff[14];
  const u16* b_in  = arena + aoff[15];
  const u16* w3    = arena + aoff[16];
  const u16* b3    = arena + aoff[17];
  const u16* w5    = arena + aoff[18];
  const u16* b5    = arena + aoff[19];
  const u16* w7    = arena + aoff[20];
  const u16* b7    = arena + aoff[21];
  const u16* w_pw  = arena + aoff[22];
  const u16* b_pw  = arena + aoff[23];
  const u16* w_out = arena + aoff[24];
  const u16* b_out = arena + aoff[25];

  float* cat1r = (float*)(ws + 24 * MB);   // [24,56)  f32, K4 -> K5,K8
  u16* qb      = (u16*)(ws + 56 * MB);     // [56,72)  K1 -> K3
  u16* kvb     = (u16*)(ws + 72 * MB);     // [72,104) K2 -> K3
  u16* obf     = (u16*)(ws + 104 * MB);    // [104,120) K3 -> K4
  u16* yb      = (u16*)(ws + 56 * MB);     // [56,88)  K5 -> K6,K7
  u16* fbuf_b  = (u16*)(ws + 88 * MB);     // [88,112) per-batch
  u16* y2b     = (u16*)(ws + 112 * MB);    // [112,144) K7 -> K8
  float* outp  = (float*)d_out;

  dim3 blk256(256);
  convert_all<<<total_blocks, 256, 0, stream>>>(ca, arena);

  // K1: q = wq @ LN(cat1; an)
  gemm1x1_mfma<128, 128, 1, true, false, false, 0, false>
      <<<dim3(HW_ / 64, 4), blk256, 0, stream>>>(f1c, f2c, wq, bq, an_g, an_b, 1e-6f,
                                                 nullptr, nullptr, qb, 0);
  // K2: kv = wkv @ LN(cat2; anc)
  gemm1x1_mfma<128, 256, 1, true, false, false, 0, false>
      <<<dim3(HW_ / 64, 4), blk256, 0, stream>>>(f2c, f1c, wkv, bkv, anc_g, anc_b, 1e-6f,
                                                 nullptr, nullptr, kvb, 0);
  // K3: attention (MFMA)
  attn_mfma<<<dim3(64, 4, 4), blk256, 0, stream>>>(qb, kvb, obf);
  // K4: cat1r = wo @ o + bo + cat1(f32 originals)
  gemm1x1_mfma<128, 128, 1, false, false, false, 4, true>
      <<<dim3(HW_ / 64, 4), blk256, 0, stream>>>(obf, nullptr, wo, bo, nullptr, nullptr, 0.f,
                                                 d_in[0], d_in[1], cat1r, 0);
  // K5: y = silu(w_in @ LN(cat1r; fn))
  gemm1x1_mfma<128, 256, 1, true, true, true, 0, false>
      <<<dim3(HW_ / 64, 4), blk256, 0, stream>>>(cat1r, nullptr, w_in, b_in, fn_g, fn_b, 1e-5f,
                                                 nullptr, nullptr, yb, 0);
  // K6/K7 per batch
  for (int b = 0; b < 4; ++b) {
    dwconv_kernel<<<dim3(32, 256), blk256, 0, stream>>>(yb + (size_t)b * 256 * HW_,
                                                        w3, b3, w5, b5, w7, b7, fbuf_b);
    gemm1x1_mfma<768, 256, 4, false, true, false, 2, false>
        <<<dim3(HW_ / 64, 1, 4), blk256, 0, stream>>>(fbuf_b, nullptr, w_pw, b_pw,
                                                      nullptr, nullptr, 0.f,
                                                      yb, nullptr, y2b, b);
  }
  // K8: out(f32) = cat1r + w_out @ y2 + b_out
  gemm1x1_mfma<256, 128, 1, false, false, false, 3, true>
      <<<dim3(HW_ / 64, 4), blk256, 0, stream>>>(y2b, nullptr, w_out, b_out,
                                                 nullptr, nullptr, 0.f,
                                                 cat1r, nullptr, outp, 0);
}

// Round 6
// 555.511 us; speedup vs baseline: 4.3612x; 1.2825x over previous
//
#include <hip/hip_runtime.h>

typedef unsigned short u16;
typedef unsigned int u32;

constexpr int H_ = 64;
constexpr int W_ = 256;
constexpr int HW_ = H_ * W_;

typedef __bf16 bf16x8 __attribute__((ext_vector_type(8)));
typedef float f32x4 __attribute__((ext_vector_type(4)));

__device__ __forceinline__ float bf2f(u16 v) { return __uint_as_float(((u32)v) << 16); }
__device__ __forceinline__ u16 f2bf(float f) {
  u32 x = __float_as_uint(f);
  u32 r = (x + 0x7fffu + ((x >> 16) & 1u)) >> 16;
  return (u16)r;
}
__device__ __forceinline__ float lo2f(u32 p) { return __uint_as_float(p << 16); }
__device__ __forceinline__ float hi2f(u32 p) { return __uint_as_float(p & 0xffff0000u); }
__device__ __forceinline__ void unpack8(uint4 v, float* f) {
  f[0] = lo2f(v.x); f[1] = hi2f(v.x);
  f[2] = lo2f(v.y); f[3] = hi2f(v.y);
  f[4] = lo2f(v.z); f[5] = hi2f(v.z);
  f[6] = lo2f(v.w); f[7] = hi2f(v.w);
}
__device__ __forceinline__ bf16x8 as_bf16x8(uint4 v) {
  union { uint4 u; bf16x8 b; } x; x.u = v; return x.b;
}

// ---------------- normalize all f32 inputs to a bf16 arena ----------------
constexpr int NT = 26;
constexpr int ELEMS_PER_BLK = 4096;
struct CvtArgs {
  const void* src[NT];
  u32 dst_off[NT];
  u32 n[NT];
  u32 blk_start[NT];
};

__global__ void convert_all(CvtArgs a, u16* __restrict__ dst) {
  const u32 bid = blockIdx.x;
  int ti = 0;
#pragma unroll
  for (int k = 1; k < NT; ++k) if (a.blk_start[k] <= bid) ti = k;
  const u32 e0 = (bid - a.blk_start[ti]) * ELEMS_PER_BLK;
  const u32 n = a.n[ti];
  u32 hi = e0 + ELEMS_PER_BLK; if (hi > n) hi = n;
  const float* sp = (const float*)a.src[ti];
  u16* d = dst + a.dst_off[ti];
  for (u32 i = e0 + threadIdx.x; i < hi; i += 256) d[i] = f2bf(sp[i]);
}

// ---------------- MFMA 1x1-conv GEMM, POS=64 ----------------
// out[b,o,p] = act(sum_c w[o,c]*x[b,c,p] + bias[o]) (+res)
// RES: 0 none, 2 bf16 single, 3 f32 single, 4 f32 dual (cat batch)
// NOG: COUT split across blockIdx.z.
template <int CIN, int COUT, int NOG, bool LN, bool SILU, bool IN_F32, int RES, bool OUT_F32>
__launch_bounds__(256)
__global__ void gemm1x1_mfma(const void* __restrict__ xA, const void* __restrict__ xB,
                             const u16* __restrict__ w, const u16* __restrict__ bias,
                             const u16* __restrict__ lng, const u16* __restrict__ lnb,
                             float lneps,
                             const void* __restrict__ resA, const void* __restrict__ resB,
                             void* __restrict__ out, int b_off) {
  static_assert(!LN || CIN == 128, "LN path assumes CIN=128");
  constexpr int POS = 64;
  constexpr int PITCH = CIN + 8;
  constexpr int MT = COUT / NOG / 64;   // M-tiles per wave
  __shared__ __align__(16) u16 xs[POS * PITCH];
  const int t = threadIdx.x;
  const int b = blockIdx.y;
  const int bo2 = b + b_off;
  const int pos0 = blockIdx.x * POS;
  const int og0 = blockIdx.z * (COUT / NOG);

  const u16* xb16 = nullptr;
  const float* xf32 = nullptr;
  if constexpr (IN_F32) {
    xf32 = ((const float*)xA) + (size_t)b * CIN * HW_;
  } else {
    const u16* basep = (const u16*)((xB != nullptr && b >= 2) ? xB : xA);
    const int bb = (xB != nullptr) ? ((b < 2) ? b : b - 2) : b;
    xb16 = basep + (size_t)bb * CIN * HW_;
  }

  // Vectorized staging: global X is [c][pos] (pos contiguous) -> coalesced
  // 16B loads, 8 (or 4) ds_write_b16 scatter into [pos][c].
  if constexpr (IN_F32) {
    constexpr int NLOAD = CIN * POS / 4;
    for (int idx = t; idx < NLOAD; idx += 256) {
      const int c = idx / (POS / 4);
      const int p4 = (idx % (POS / 4)) * 4;
      float4 v = *(const float4*)(xf32 + (size_t)c * HW_ + pos0 + p4);
      u16* row = xs + p4 * PITCH + c;
      row[0]         = f2bf(v.x);
      row[PITCH]     = f2bf(v.y);
      row[2 * PITCH] = f2bf(v.z);
      row[3 * PITCH] = f2bf(v.w);
    }
  } else {
    constexpr int NLOAD = CIN * POS / 8;
    for (int idx = t; idx < NLOAD; idx += 256) {
      const int c = idx / (POS / 8);
      const int p8 = (idx % (POS / 8)) * 8;
      uint4 v = *(const uint4*)(xb16 + (size_t)c * HW_ + pos0 + p8);
      u16* row = xs + p8 * PITCH + c;
      row[0]         = (u16)v.x; row[PITCH]     = (u16)(v.x >> 16);
      row[2 * PITCH] = (u16)v.y; row[3 * PITCH] = (u16)(v.y >> 16);
      row[4 * PITCH] = (u16)v.z; row[5 * PITCH] = (u16)(v.z >> 16);
      row[6 * PITCH] = (u16)v.w; row[7 * PITCH] = (u16)(v.w >> 16);
    }
  }
  __syncthreads();

  if constexpr (LN) {
    __shared__ float red1[256], red2[256], stm[64], str[64];
    const int p = t & 63, part = t >> 6;
    float s = 0.f, sq = 0.f;
#pragma unroll
    for (int k = 0; k < 32; k += 8) {
      uint4 v = *(const uint4*)(xs + p * PITCH + part * 32 + k);
      float f[8]; unpack8(v, f);
#pragma unroll
      for (int j = 0; j < 8; ++j) { s += f[j]; sq += f[j] * f[j]; }
    }
    red1[part * 64 + p] = s; red2[part * 64 + p] = sq;
    __syncthreads();
    if (t < 64) {
      float ss = red1[t] + red1[64 + t] + red1[128 + t] + red1[192 + t];
      float qq = red2[t] + red2[64 + t] + red2[128 + t] + red2[192 + t];
      float m = ss * (1.0f / CIN);
      float var = qq * (1.0f / CIN) - m * m;
      var = var < 0.f ? 0.f : var;
      stm[t] = m; str[t] = rsqrtf(var + lneps);
    }
    __syncthreads();
    const float m = stm[p], r = str[p];
#pragma unroll
    for (int k = 0; k < 32; k += 8) {
      const int c = part * 32 + k;
      uint4 v = *(const uint4*)(xs + p * PITCH + c);
      float f[8]; unpack8(v, f);
      u32 pk[4];
#pragma unroll
      for (int j = 0; j < 8; j += 2) {
        float g0 = bf2f(lng[c + j]), be0 = bf2f(lnb[c + j]);
        float g1 = bf2f(lng[c + j + 1]), be1 = bf2f(lnb[c + j + 1]);
        u16 lo = f2bf((f[j] - m) * r * g0 + be0);
        u16 hi = f2bf((f[j + 1] - m) * r * g1 + be1);
        pk[j >> 1] = (u32)lo | ((u32)hi << 16);
      }
      uint4 ov; ov.x = pk[0]; ov.y = pk[1]; ov.z = pk[2]; ov.w = pk[3];
      *(uint4*)(xs + p * PITCH + c) = ov;
    }
    __syncthreads();
  }

  const int lane = t & 63, wv = t >> 6;
  const int lo16 = lane & 15, quad = lane >> 4;
  const int orow0 = og0 + wv * MT * 16;
  const int qrow = quad * 4;

  f32x4 acc[MT][4];
#pragma unroll
  for (int mt = 0; mt < MT; ++mt) {
#pragma unroll
    for (int r = 0; r < 4; ++r) {
      const float bv = bf2f(bias[orow0 + mt * 16 + qrow + r]);
#pragma unroll
      for (int nt = 0; nt < 4; ++nt) acc[mt][nt][r] = bv;
    }
  }

  const u16* xsl = xs + lo16 * PITCH + quad * 8;
  const u16* wl = w + (size_t)(orow0 + lo16) * CIN + quad * 8;

#pragma unroll 2
  for (int kc = 0; kc < CIN / 32; ++kc) {
    const int c0 = kc * 32;
    bf16x8 bfr[4];
#pragma unroll
    for (int nt = 0; nt < 4; ++nt)
      bfr[nt] = as_bf16x8(*(const uint4*)(xsl + nt * 16 * PITCH + c0));
#pragma unroll
    for (int mt = 0; mt < MT; ++mt) {
      bf16x8 afr = as_bf16x8(*(const uint4*)(wl + (size_t)mt * 16 * CIN + c0));
#pragma unroll
      for (int nt = 0; nt < 4; ++nt)
        acc[mt][nt] = __builtin_amdgcn_mfma_f32_16x16x32_bf16(afr, bfr[nt], acc[mt][nt], 0, 0, 0);
    }
  }

#pragma unroll
  for (int mt = 0; mt < MT; ++mt) {
#pragma unroll
    for (int nt = 0; nt < 4; ++nt) {
#pragma unroll
      for (int r = 0; r < 4; ++r) {
        const int o = orow0 + mt * 16 + qrow + r;
        const int p = pos0 + nt * 16 + lo16;
        float v = acc[mt][nt][r];
        if constexpr (SILU) v = v / (1.0f + __expf(-v));
        const size_t gidx = ((size_t)bo2 * COUT + o) * HW_ + p;
        if constexpr (RES == 2) {
          v += bf2f(((const u16*)resA)[gidx]);
        } else if constexpr (RES == 3) {
          v += ((const float*)resA)[gidx];
        } else if constexpr (RES == 4) {
          const int bl = (bo2 < 2) ? bo2 : bo2 - 2;
          const float* rb = (bo2 < 2) ? (const float*)resA : (const float*)resB;
          v += rb[((size_t)bl * COUT + o) * HW_ + p];
        }
        if constexpr (OUT_F32) ((float*)out)[gidx] = v;
        else                   ((u16*)out)[gidx] = f2bf(v);
      }
    }
  }
}

// ---------------- MFMA attention ----------------
// One block per (b,n,h). Wave wv exclusively owns qT rows {ii*64+wv*16..+15}
// and its Pl slice, so NO in-loop __syncthreads is needed (intra-wave LDS
// ordering is compiler-enforced); single barrier before the final store.
__launch_bounds__(256)
__global__ void attn_mfma(const u16* __restrict__ qb, const u16* __restrict__ kvb,
                          u16* __restrict__ ob) {
  constexpr int PA = 40;    // qT/kT pitch (u16)
  constexpr int PJ = 264;   // vT/P pitch (u16)
  __shared__ __align__(16) u16 qT[256 * PA];   // rows reused for O after consumption
  __shared__ __align__(16) u16 kT[256 * PA];
  __shared__ __align__(16) u16 vT[32 * PJ];
  __shared__ __align__(16) u16 Pl[4 * 16 * PJ];
  const int t = threadIdx.x;
  const int h = blockIdx.x, n = blockIdx.y, b = blockIdx.z;
  const size_t qbase = ((size_t)(b * 128 + n * 32)) * HW_ + (size_t)h * W_;
  const size_t kbase = ((size_t)(b * 256 + n * 32)) * HW_ + (size_t)h * W_;
  const size_t vbase = ((size_t)(b * 256 + 128 + n * 32)) * HW_ + (size_t)h * W_;

#pragma unroll
  for (int d8 = 0; d8 < 4; ++d8) {
    u32 pk[4];
#pragma unroll
    for (int j = 0; j < 4; ++j) {
      u32 lo = qb[qbase + (size_t)(d8 * 8 + 2 * j) * HW_ + t];
      u32 hi = qb[qbase + (size_t)(d8 * 8 + 2 * j + 1) * HW_ + t];
      pk[j] = lo | (hi << 16);
    }
    *(uint4*)(qT + t * PA + d8 * 8) = make_uint4(pk[0], pk[1], pk[2], pk[3]);
#pragma unroll
    for (int j = 0; j < 4; ++j) {
      u32 lo = kvb[kbase + (size_t)(d8 * 8 + 2 * j) * HW_ + t];
      u32 hi = kvb[kbase + (size_t)(d8 * 8 + 2 * j + 1) * HW_ + t];
      pk[j] = lo | (hi << 16);
    }
    *(uint4*)(kT + t * PA + d8 * 8) = make_uint4(pk[0], pk[1], pk[2], pk[3]);
  }
#pragma unroll
  for (int k = 0; k < 16; ++k) {
    const int idx = k * 256 + t;
    const int d = idx >> 7, p2 = (idx & 127) * 2;
    u32 v = *(const u32*)(kvb + vbase + (size_t)d * HW_ + p2);
    *(u32*)(vT + d * PJ + p2) = v;
  }
  __syncthreads();

  const int lane = t & 63, wv = t >> 6;
  const int lo16 = lane & 15, quad = lane >> 4;
  const float scale = 0.17677669529663687f;  // 32^-0.5
  const float renorm = 1.0f / (1.0f + 256.0f * 1e-6f);
  u16* Pw = Pl + wv * 16 * PJ;

  for (int ii = 0; ii < 4; ++ii) {
    const int i0 = ii * 64 + wv * 16;
    bf16x8 qa = as_bf16x8(*(const uint4*)(qT + (i0 + lo16) * PA + quad * 8));
    f32x4 s[16];
#pragma unroll
    for (int jt = 0; jt < 16; ++jt) {
      bf16x8 kb = as_bf16x8(*(const uint4*)(kT + (jt * 16 + lo16) * PA + quad * 8));
      f32x4 z = {0.f, 0.f, 0.f, 0.f};
      s[jt] = __builtin_amdgcn_mfma_f32_16x16x32_bf16(qa, kb, z, 0, 0, 0);
    }
#pragma unroll
    for (int r = 0; r < 4; ++r) {
      float m = s[0][r];
#pragma unroll
      for (int jt = 1; jt < 16; ++jt) m = fmaxf(m, s[jt][r]);
      m *= scale;
#pragma unroll
      for (int off = 1; off <= 8; off <<= 1) m = fmaxf(m, __shfl_xor(m, off, 64));
      float sum = 0.f;
#pragma unroll
      for (int jt = 0; jt < 16; ++jt) {
        float e = __expf(s[jt][r] * scale - m);
        s[jt][r] = e; sum += e;
      }
#pragma unroll
      for (int off = 1; off <= 8; off <<= 1) sum += __shfl_xor(sum, off, 64);
      const float inv = 1.0f / sum;
#pragma unroll
      for (int jt = 0; jt < 16; ++jt)
        Pw[(quad * 4 + r) * PJ + jt * 16 + lo16] = f2bf((s[jt][r] * inv + 1e-6f) * renorm);
    }
    // wave-private P: no barrier needed
    f32x4 o0 = {0.f, 0.f, 0.f, 0.f}, o1 = {0.f, 0.f, 0.f, 0.f};
#pragma unroll
    for (int kt = 0; kt < 8; ++kt) {
      bf16x8 pa = as_bf16x8(*(const uint4*)(Pw + lo16 * PJ + kt * 32 + quad * 8));
      bf16x8 v0 = as_bf16x8(*(const uint4*)(vT + lo16 * PJ + kt * 32 + quad * 8));
      bf16x8 v1 = as_bf16x8(*(const uint4*)(vT + (16 + lo16) * PJ + kt * 32 + quad * 8));
      o0 = __builtin_amdgcn_mfma_f32_16x16x32_bf16(pa, v0, o0, 0, 0, 0);
      o1 = __builtin_amdgcn_mfma_f32_16x16x32_bf16(pa, v1, o1, 0, 0, 0);
    }
    // O -> this wave's own qT rows (already consumed by this wave)
#pragma unroll
    for (int r = 0; r < 4; ++r) {
      qT[(i0 + quad * 4 + r) * PA + lo16] = f2bf(o0[r]);
      qT[(i0 + quad * 4 + r) * PA + 16 + lo16] = f2bf(o1[r]);
    }
  }
  __syncthreads();
  for (int d = 0; d < 32; ++d) ob[qbase + (size_t)d * HW_ + t] = qT[t * PA + d];
}

// ---------------- fused depthwise 3/5/7, single batch ----------------
// Thread = 2 adjacent x outputs x 1 row; row window = 5 aligned u32 LDS reads.
__launch_bounds__(256)
__global__ void dwconv_kernel(const u16* __restrict__ yB,
                              const u16* __restrict__ w3, const u16* __restrict__ b3,
                              const u16* __restrict__ w5, const u16* __restrict__ b5,
                              const u16* __restrict__ w7, const u16* __restrict__ b7,
                              u16* __restrict__ fB) {
  constexpr int LW = 70, LH = 14, LP = 72;
  __shared__ u16 tile[LH * LP];
  __shared__ float wf7[49], wf5[25], wf3[9];
  const int t = threadIdx.x;
  const int c = blockIdx.y;
  const int tw = blockIdx.x & 3, th = blockIdx.x >> 2;
  const int w0 = tw * 64, h0 = th * 8;
  const u16* src = yB + (size_t)c * HW_;

  if (t < 49) wf7[t] = bf2f(w7[c * 49 + t]);
  if (t >= 64 && t < 89) wf5[t - 64] = bf2f(w5[c * 25 + (t - 64)]);
  if (t >= 96 && t < 105) wf3[t - 96] = bf2f(w3[c * 9 + (t - 96)]);

  for (int idx = t; idx < LH * LW; idx += 256) {
    const int r = idx / LW, cc = idx - r * LW;
    const int gh = h0 + r - 3, gw = w0 + cc - 3;
    u16 v = 0;
    if (gh >= 0 && gh < H_ && gw >= 0 && gw < W_) v = src[gh * W_ + gw];
    tile[r * LP + cc] = v;
  }
  __syncthreads();

  const int x0 = (t & 31) * 2;   // 0..62 (even)
  const int hh = t >> 5;         // 0..7
  float a3x = 0.f, a3y = 0.f, a5x = 0.f, a5y = 0.f, a7x = 0.f, a7y = 0.f;
#pragma unroll
  for (int rr = 0; rr < 7; ++rr) {
    const u16* trow = tile + (hh + rr) * LP + x0;
    float f[10];
#pragma unroll
    for (int k = 0; k < 5; ++k) {
      u32 v = *(const u32*)(trow + 2 * k);   // (hh+rr)*LP + x0 even -> 4B aligned
      f[2 * k] = lo2f(v); f[2 * k + 1] = hi2f(v);
    }
#pragma unroll
    for (int dx = 0; dx < 7; ++dx) {
      const float wv = wf7[rr * 7 + dx];
      a7x += wv * f[dx]; a7y += wv * f[dx + 1];
    }
    if (rr >= 1 && rr <= 5) {
#pragma unroll
      for (int dx = 0; dx < 5; ++dx) {
        const float wv = wf5[(rr - 1) * 5 + dx];
        a5x += wv * f[dx + 1]; a5y += wv * f[dx + 2];
      }
    }
    if (rr >= 2 && rr <= 4) {
#pragma unroll
      for (int dx = 0; dx < 3; ++dx) {
        const float wv = wf3[(rr - 2) * 3 + dx];
        a3x += wv * f[dx + 2]; a3y += wv * f[dx + 3];
      }
    }
  }
  const float B3v = bf2f(b3[c]), B5v = bf2f(b5[c]), B7v = bf2f(b7[c]);
  const size_t o0 = (size_t)c * HW_ + (size_t)(h0 + hh) * W_ + (w0 + x0);
  *(u32*)(fB + o0) = (u32)f2bf(a3x + B3v) | ((u32)f2bf(a3y + B3v) << 16);
  *(u32*)(fB + o0 + (size_t)256 * HW_) = (u32)f2bf(a5x + B5v) | ((u32)f2bf(a5y + B5v) << 16);
  *(u32*)(fB + o0 + (size_t)512 * HW_) = (u32)f2bf(a7x + B7v) | ((u32)f2bf(a7y + B7v) << 16);
}

extern "C" void kernel_launch(void* const* d_in, const int* in_sizes, int n_in,
                              void* d_out, int out_size, void* d_ws, size_t ws_size,
                              hipStream_t stream) {
  (void)out_size; (void)ws_size; (void)n_in;
  char* ws = (char*)d_ws;
  const size_t MB = 1ull << 20;

  u16* arena = (u16*)ws;
  CvtArgs ca;
  u32 off = 0, blk = 0;
  u32 aoff[NT];
  for (int i = 0; i < NT; ++i) {
    ca.src[i] = d_in[i];
    ca.n[i] = (u32)in_sizes[i];
    ca.dst_off[i] = off;
    aoff[i] = off;
    ca.blk_start[i] = blk;
    off += (ca.n[i] + 15u) & ~15u;
    blk += (ca.n[i] + ELEMS_PER_BLK - 1) / ELEMS_PER_BLK;
  }
  const u32 total_blocks = blk;

  const u16* f1c   = arena + aoff[0];
  const u16* f2c   = arena + aoff[1];
  const u16* an_g  = arena + aoff[2];
  const u16* an_b  = arena + aoff[3];
  const u16* anc_g = arena + aoff[4];
  const u16* anc_b = arena + aoff[5];
  const u16* wq    = arena + aoff[6];
  const u16* bq    = arena + aoff[7];
  const u16* wkv   = arena + aoff[8];
  const u16* bkv   = arena + aoff[9];
  const u16* wo    = arena + aoff[10];
  const u16* bo    = arena + aoff[11];
  const u16* fn_g  = arena + aoff[12];
  const u16* fn_b  = arena + aoff[13];
  const u16* w_in  = arena + aoff[14];
  const u16* b_in  = arena + aoff[15];
  const u16* w3    = arena + aoff[16];
  const u16* b3    = arena + aoff[17];
  const u16* w5    = arena + aoff[18];
  const u16* b5    = arena + aoff[19];
  const u16* w7    = arena + aoff[20];
  const u16* b7    = arena + aoff[21];
  const u16* w_pw  = arena + aoff[22];
  const u16* b_pw  = arena + aoff[23];
  const u16* w_out = arena + aoff[24];
  const u16* b_out = arena + aoff[25];

  // overlay (peak 146MB): fbuf_b needs 768*16384*2 = 25.17MB -> 26MB slot
  float* cat1r = (float*)(ws + 24 * MB);   // [24,56)  f32, K4 -> K5,K8
  u16* qb      = (u16*)(ws + 56 * MB);     // [56,72)  K1 -> K3
  u16* kvb     = (u16*)(ws + 72 * MB);     // [72,104) K2 -> K3
  u16* obf     = (u16*)(ws + 104 * MB);    // [104,120) K3 -> K4
  u16* yb      = (u16*)(ws + 56 * MB);     // [56,88)  K5 -> K6,K7
  u16* fbuf_b  = (u16*)(ws + 88 * MB);     // [88,114) per-batch (25.17MB)
  u16* y2b     = (u16*)(ws + 114 * MB);    // [114,146) K7 -> K8
  float* outp  = (float*)d_out;

  dim3 blk256(256);
  convert_all<<<total_blocks, 256, 0, stream>>>(ca, arena);

  // K1: q = wq @ LN(cat1; an)
  gemm1x1_mfma<128, 128, 1, true, false, false, 0, false>
      <<<dim3(HW_ / 64, 4), blk256, 0, stream>>>(f1c, f2c, wq, bq, an_g, an_b, 1e-6f,
                                                 nullptr, nullptr, qb, 0);
  // K2: kv = wkv @ LN(cat2; anc)
  gemm1x1_mfma<128, 256, 1, true, false, false, 0, false>
      <<<dim3(HW_ / 64, 4), blk256, 0, stream>>>(f2c, f1c, wkv, bkv, anc_g, anc_b, 1e-6f,
                                                 nullptr, nullptr, kvb, 0);
  // K3: attention (MFMA)
  attn_mfma<<<dim3(64, 4, 4), blk256, 0, stream>>>(qb, kvb, obf);
  // K4: cat1r = wo @ o + bo + cat1(f32 originals)
  gemm1x1_mfma<128, 128, 1, false, false, false, 4, true>
      <<<dim3(HW_ / 64, 4), blk256, 0, stream>>>(obf, nullptr, wo, bo, nullptr, nullptr, 0.f,
                                                 d_in[0], d_in[1], cat1r, 0);
  // K5: y = silu(w_in @ LN(cat1r; fn))
  gemm1x1_mfma<128, 256, 1, true, true, true, 0, false>
      <<<dim3(HW_ / 64, 4), blk256, 0, stream>>>(cat1r, nullptr, w_in, b_in, fn_g, fn_b, 1e-5f,
                                                 nullptr, nullptr, yb, 0);
  // K6/K7 per batch
  for (int b = 0; b < 4; ++b) {
    dwconv_kernel<<<dim3(32, 256), blk256, 0, stream>>>(yb + (size_t)b * 256 * HW_,
                                                        w3, b3, w5, b5, w7, b7, fbuf_b);
    gemm1x1_mfma<768, 256, 4, false, true, false, 2, false>
        <<<dim3(HW_ / 64, 1, 4), blk256, 0, stream>>>(fbuf_b, nullptr, w_pw, b_pw,
                                                      nullptr, nullptr, 0.f,
                                                      yb, nullptr, y2b, b);
  }
  // K8: out(f32) = cat1r + w_out @ y2 + b_out
  gemm1x1_mfma<256, 128, 1, false, false, false, 3, true>
      <<<dim3(HW_ / 64, 4), blk256, 0, stream>>>(y2b, nullptr, w_out, b_out,
                                                 nullptr, nullptr, 0.f,
                                                 cat1r, nullptr, outp, 0);
}

// Round 7
// 481.148 us; speedup vs baseline: 5.0352x; 1.1546x over previous
//
#include <hip/hip_runtime.h>

typedef unsigned short u16;
typedef unsigned int u32;

constexpr int H_ = 64;
constexpr int W_ = 256;
constexpr int HW_ = H_ * W_;

typedef __bf16 bf16x8 __attribute__((ext_vector_type(8)));
typedef float f32x4 __attribute__((ext_vector_type(4)));

__device__ __forceinline__ float bf2f(u16 v) { return __uint_as_float(((u32)v) << 16); }
__device__ __forceinline__ u16 f2bf(float f) {
  u32 x = __float_as_uint(f);
  u32 r = (x + 0x7fffu + ((x >> 16) & 1u)) >> 16;
  return (u16)r;
}
__device__ __forceinline__ float lo2f(u32 p) { return __uint_as_float(p << 16); }
__device__ __forceinline__ float hi2f(u32 p) { return __uint_as_float(p & 0xffff0000u); }
__device__ __forceinline__ void unpack8(uint4 v, float* f) {
  f[0] = lo2f(v.x); f[1] = hi2f(v.x);
  f[2] = lo2f(v.y); f[3] = hi2f(v.y);
  f[4] = lo2f(v.z); f[5] = hi2f(v.z);
  f[6] = lo2f(v.w); f[7] = hi2f(v.w);
}
__device__ __forceinline__ bf16x8 as_bf16x8(uint4 v) {
  union { uint4 u; bf16x8 b; } x; x.u = v; return x.b;
}
// bank swizzle: channel c of position p lives at column c ^ (((p>>3)&3)<<3).
// Bits 3-4 only -> never aliases 32-aligned k-offsets; keeps 8-blocks intact.
__device__ __forceinline__ int swz(int p, int c) { return c ^ (((p >> 3) & 3) << 3); }

// ---------------- normalize all f32 inputs to a bf16 arena ----------------
constexpr int NT = 26;
constexpr int ELEMS_PER_BLK = 4096;
struct CvtArgs {
  const void* src[NT];
  u32 dst_off[NT];
  u32 n[NT];
  u32 blk_start[NT];
};

__global__ void convert_all(CvtArgs a, u16* __restrict__ dst) {
  const u32 bid = blockIdx.x;
  int ti = 0;
#pragma unroll
  for (int k = 1; k < NT; ++k) if (a.blk_start[k] <= bid) ti = k;
  const u32 e0 = (bid - a.blk_start[ti]) * ELEMS_PER_BLK;
  const u32 n = a.n[ti];
  u32 hi = e0 + ELEMS_PER_BLK; if (hi > n) hi = n;
  const float* sp = (const float*)a.src[ti];
  u16* d = dst + a.dst_off[ti];
  for (u32 i = e0 + threadIdx.x; i < hi; i += 256) d[i] = f2bf(sp[i]);
}

// ---------------- MFMA 1x1-conv GEMM, POS=64 ----------------
// out[b,o,p] = act(sum_c w[o,c]*x[b,c,p] + bias[o]) (+res)
// RES: 0 none, 2 bf16 single, 3 f32 single, 4 f32 dual (cat batch)
// NOG: COUT split across blockIdx.z. MT = COUT/NOG/64 M-tiles per wave.
template <int CIN, int COUT, int NOG, bool LN, bool SILU, bool IN_F32, int RES, bool OUT_F32>
__launch_bounds__(256)
__global__ void gemm1x1_mfma(const void* __restrict__ xA, const void* __restrict__ xB,
                             const u16* __restrict__ w, const u16* __restrict__ bias,
                             const u16* __restrict__ lng, const u16* __restrict__ lnb,
                             float lneps,
                             const void* __restrict__ resA, const void* __restrict__ resB,
                             void* __restrict__ out, int b_off) {
  static_assert(!LN || CIN == 128, "LN path assumes CIN=128");
  constexpr int POS = 64;
  constexpr int PITCH = CIN + 8;
  constexpr int MT = COUT / NOG / 64;
  __shared__ __align__(16) u16 xs[POS * PITCH];
  const int t = threadIdx.x;
  const int b = blockIdx.y;
  const int bo2 = b + b_off;
  const int pos0 = blockIdx.x * POS;
  const int og0 = blockIdx.z * (COUT / NOG);

  const u16* xb16 = nullptr;
  const float* xf32 = nullptr;
  if constexpr (IN_F32) {
    xf32 = ((const float*)xA) + (size_t)b * CIN * HW_;
  } else {
    const u16* basep = (const u16*)((xB != nullptr && b >= 2) ? xB : xA);
    const int bb = (xB != nullptr) ? ((b < 2) ? b : b - 2) : b;
    xb16 = basep + (size_t)bb * CIN * HW_;
  }

  // Vectorized staging with bank swizzle (write conflicts 8-way -> 2-way).
  if constexpr (IN_F32) {
    constexpr int NLOAD = CIN * POS / 4;
    for (int idx = t; idx < NLOAD; idx += 256) {
      const int c = idx / (POS / 4);
      const int p4 = (idx % (POS / 4)) * 4;
      float4 v = *(const float4*)(xf32 + (size_t)c * HW_ + pos0 + p4);
      const int csw = swz(p4, c);     // p4..p4+3 share (p>>3)
      u16* row = xs + p4 * PITCH + csw;
      row[0]         = f2bf(v.x);
      row[PITCH]     = f2bf(v.y);
      row[2 * PITCH] = f2bf(v.z);
      row[3 * PITCH] = f2bf(v.w);
    }
  } else {
    constexpr int NLOAD = CIN * POS / 8;
    for (int idx = t; idx < NLOAD; idx += 256) {
      const int c = idx / (POS / 8);
      const int p8 = (idx % (POS / 8)) * 8;
      uint4 v = *(const uint4*)(xb16 + (size_t)c * HW_ + pos0 + p8);
      const int csw = swz(p8, c);     // p8..p8+7 share (p>>3)
      u16* row = xs + p8 * PITCH + csw;
      row[0]         = (u16)v.x; row[PITCH]     = (u16)(v.x >> 16);
      row[2 * PITCH] = (u16)v.y; row[3 * PITCH] = (u16)(v.y >> 16);
      row[4 * PITCH] = (u16)v.z; row[5 * PITCH] = (u16)(v.z >> 16);
      row[6 * PITCH] = (u16)v.w; row[7 * PITCH] = (u16)(v.w >> 16);
    }
  }
  __syncthreads();

  if constexpr (LN) {
    __shared__ float red1[256], red2[256], stm[64], str[64];
    const int p = t & 63, part = t >> 6;
    const int xorp = ((p >> 3) & 3) << 3;
    float s = 0.f, sq = 0.f;
#pragma unroll
    for (int k = 0; k < 32; k += 8) {
      uint4 v = *(const uint4*)(xs + p * PITCH + ((part * 32 + k) ^ xorp));
      float f[8]; unpack8(v, f);
#pragma unroll
      for (int j = 0; j < 8; ++j) { s += f[j]; sq += f[j] * f[j]; }
    }
    red1[part * 64 + p] = s; red2[part * 64 + p] = sq;
    __syncthreads();
    if (t < 64) {
      float ss = red1[t] + red1[64 + t] + red1[128 + t] + red1[192 + t];
      float qq = red2[t] + red2[64 + t] + red2[128 + t] + red2[192 + t];
      float m = ss * (1.0f / CIN);
      float var = qq * (1.0f / CIN) - m * m;
      var = var < 0.f ? 0.f : var;
      stm[t] = m; str[t] = rsqrtf(var + lneps);
    }
    __syncthreads();
    const float m = stm[p], r = str[p];
#pragma unroll
    for (int k = 0; k < 32; k += 8) {
      const int c = part * 32 + k;       // true channel base; col swizzled
      uint4 v = *(const uint4*)(xs + p * PITCH + (c ^ xorp));
      float f[8]; unpack8(v, f);
      u32 pk[4];
#pragma unroll
      for (int j = 0; j < 8; j += 2) {
        float g0 = bf2f(lng[c + j]), be0 = bf2f(lnb[c + j]);
        float g1 = bf2f(lng[c + j + 1]), be1 = bf2f(lnb[c + j + 1]);
        u16 lo = f2bf((f[j] - m) * r * g0 + be0);
        u16 hi = f2bf((f[j + 1] - m) * r * g1 + be1);
        pk[j >> 1] = (u32)lo | ((u32)hi << 16);
      }
      uint4 ov; ov.x = pk[0]; ov.y = pk[1]; ov.z = pk[2]; ov.w = pk[3];
      *(uint4*)(xs + p * PITCH + (c ^ xorp)) = ov;
    }
    __syncthreads();
  }

  const int lane = t & 63, wv = t >> 6;
  const int lo16 = lane & 15, quad = lane >> 4;
  const int orow0 = og0 + wv * MT * 16;
  const int qrow = quad * 4;

  f32x4 acc[MT][4];
#pragma unroll
  for (int mt = 0; mt < MT; ++mt) {
#pragma unroll
    for (int r = 0; r < 4; ++r) {
      const float bv = bf2f(bias[orow0 + mt * 16 + qrow + r]);
#pragma unroll
      for (int nt = 0; nt < 4; ++nt) acc[mt][nt][r] = bv;
    }
  }

  // per-N-tile swizzled base pointers (c0 is 32-aligned -> additive)
  const u16* xb[4];
#pragma unroll
  for (int nt = 0; nt < 4; ++nt) {
    const int row = nt * 16 + lo16;
    xb[nt] = xs + row * PITCH + (quad * 8 ^ ((((row >> 3) & 3)) << 3));
  }
  const u16* wl = w + (size_t)(orow0 + lo16) * CIN + quad * 8;

#pragma unroll 2
  for (int kc = 0; kc < CIN / 32; ++kc) {
    const int c0 = kc * 32;
    bf16x8 bfr[4];
#pragma unroll
    for (int nt = 0; nt < 4; ++nt)
      bfr[nt] = as_bf16x8(*(const uint4*)(xb[nt] + c0));
#pragma unroll
    for (int mt = 0; mt < MT; ++mt) {
      bf16x8 afr = as_bf16x8(*(const uint4*)(wl + (size_t)mt * 16 * CIN + c0));
#pragma unroll
      for (int nt = 0; nt < 4; ++nt)
        acc[mt][nt] = __builtin_amdgcn_mfma_f32_16x16x32_bf16(afr, bfr[nt], acc[mt][nt], 0, 0, 0);
    }
  }

#pragma unroll
  for (int mt = 0; mt < MT; ++mt) {
#pragma unroll
    for (int nt = 0; nt < 4; ++nt) {
#pragma unroll
      for (int r = 0; r < 4; ++r) {
        const int o = orow0 + mt * 16 + qrow + r;
        const int p = pos0 + nt * 16 + lo16;
        float v = acc[mt][nt][r];
        if constexpr (SILU) v = v / (1.0f + __expf(-v));
        const size_t gidx = ((size_t)bo2 * COUT + o) * HW_ + p;
        if constexpr (RES == 2) {
          v += bf2f(((const u16*)resA)[gidx]);
        } else if constexpr (RES == 3) {
          v += ((const float*)resA)[gidx];
        } else if constexpr (RES == 4) {
          const int bl = (bo2 < 2) ? bo2 : bo2 - 2;
          const float* rb = (bo2 < 2) ? (const float*)resA : (const float*)resB;
          v += rb[((size_t)bl * COUT + o) * HW_ + p];
        }
        if constexpr (OUT_F32) ((float*)out)[gidx] = v;
        else                   ((u16*)out)[gidx] = f2bf(v);
      }
    }
  }
}

// ---------------- MFMA attention (unchanged this round) ----------------
__launch_bounds__(256)
__global__ void attn_mfma(const u16* __restrict__ qb, const u16* __restrict__ kvb,
                          u16* __restrict__ ob) {
  constexpr int PA = 40;
  constexpr int PJ = 264;
  __shared__ __align__(16) u16 qT[256 * PA];
  __shared__ __align__(16) u16 kT[256 * PA];
  __shared__ __align__(16) u16 vT[32 * PJ];
  __shared__ __align__(16) u16 Pl[4 * 16 * PJ];
  const int t = threadIdx.x;
  const int h = blockIdx.x, n = blockIdx.y, b = blockIdx.z;
  const size_t qbase = ((size_t)(b * 128 + n * 32)) * HW_ + (size_t)h * W_;
  const size_t kbase = ((size_t)(b * 256 + n * 32)) * HW_ + (size_t)h * W_;
  const size_t vbase = ((size_t)(b * 256 + 128 + n * 32)) * HW_ + (size_t)h * W_;

#pragma unroll
  for (int d8 = 0; d8 < 4; ++d8) {
    u32 pk[4];
#pragma unroll
    for (int j = 0; j < 4; ++j) {
      u32 lo = qb[qbase + (size_t)(d8 * 8 + 2 * j) * HW_ + t];
      u32 hi = qb[qbase + (size_t)(d8 * 8 + 2 * j + 1) * HW_ + t];
      pk[j] = lo | (hi << 16);
    }
    *(uint4*)(qT + t * PA + d8 * 8) = make_uint4(pk[0], pk[1], pk[2], pk[3]);
#pragma unroll
    for (int j = 0; j < 4; ++j) {
      u32 lo = kvb[kbase + (size_t)(d8 * 8 + 2 * j) * HW_ + t];
      u32 hi = kvb[kbase + (size_t)(d8 * 8 + 2 * j + 1) * HW_ + t];
      pk[j] = lo | (hi << 16);
    }
    *(uint4*)(kT + t * PA + d8 * 8) = make_uint4(pk[0], pk[1], pk[2], pk[3]);
  }
#pragma unroll
  for (int k = 0; k < 16; ++k) {
    const int idx = k * 256 + t;
    const int d = idx >> 7, p2 = (idx & 127) * 2;
    u32 v = *(const u32*)(kvb + vbase + (size_t)d * HW_ + p2);
    *(u32*)(vT + d * PJ + p2) = v;
  }
  __syncthreads();

  const int lane = t & 63, wv = t >> 6;
  const int lo16 = lane & 15, quad = lane >> 4;
  const float scale = 0.17677669529663687f;
  const float renorm = 1.0f / (1.0f + 256.0f * 1e-6f);
  u16* Pw = Pl + wv * 16 * PJ;

  for (int ii = 0; ii < 4; ++ii) {
    const int i0 = ii * 64 + wv * 16;
    bf16x8 qa = as_bf16x8(*(const uint4*)(qT + (i0 + lo16) * PA + quad * 8));
    f32x4 s[16];
#pragma unroll
    for (int jt = 0; jt < 16; ++jt) {
      bf16x8 kb = as_bf16x8(*(const uint4*)(kT + (jt * 16 + lo16) * PA + quad * 8));
      f32x4 z = {0.f, 0.f, 0.f, 0.f};
      s[jt] = __builtin_amdgcn_mfma_f32_16x16x32_bf16(qa, kb, z, 0, 0, 0);
    }
#pragma unroll
    for (int r = 0; r < 4; ++r) {
      float m = s[0][r];
#pragma unroll
      for (int jt = 1; jt < 16; ++jt) m = fmaxf(m, s[jt][r]);
      m *= scale;
#pragma unroll
      for (int off = 1; off <= 8; off <<= 1) m = fmaxf(m, __shfl_xor(m, off, 64));
      float sum = 0.f;
#pragma unroll
      for (int jt = 0; jt < 16; ++jt) {
        float e = __expf(s[jt][r] * scale - m);
        s[jt][r] = e; sum += e;
      }
#pragma unroll
      for (int off = 1; off <= 8; off <<= 1) sum += __shfl_xor(sum, off, 64);
      const float inv = 1.0f / sum;
#pragma unroll
      for (int jt = 0; jt < 16; ++jt)
        Pw[(quad * 4 + r) * PJ + jt * 16 + lo16] = f2bf((s[jt][r] * inv + 1e-6f) * renorm);
    }
    f32x4 o0 = {0.f, 0.f, 0.f, 0.f}, o1 = {0.f, 0.f, 0.f, 0.f};
#pragma unroll
    for (int kt = 0; kt < 8; ++kt) {
      bf16x8 pa = as_bf16x8(*(const uint4*)(Pw + lo16 * PJ + kt * 32 + quad * 8));
      bf16x8 v0 = as_bf16x8(*(const uint4*)(vT + lo16 * PJ + kt * 32 + quad * 8));
      bf16x8 v1 = as_bf16x8(*(const uint4*)(vT + (16 + lo16) * PJ + kt * 32 + quad * 8));
      o0 = __builtin_amdgcn_mfma_f32_16x16x32_bf16(pa, v0, o0, 0, 0, 0);
      o1 = __builtin_amdgcn_mfma_f32_16x16x32_bf16(pa, v1, o1, 0, 0, 0);
    }
#pragma unroll
    for (int r = 0; r < 4; ++r) {
      qT[(i0 + quad * 4 + r) * PA + lo16] = f2bf(o0[r]);
      qT[(i0 + quad * 4 + r) * PA + 16 + lo16] = f2bf(o1[r]);
    }
  }
  __syncthreads();
  for (int d = 0; d < 32; ++d) ob[qbase + (size_t)d * HW_ + t] = qT[t * PA + d];
}

// ---------------- fused depthwise 3/5/7, single batch ----------------
__launch_bounds__(256)
__global__ void dwconv_kernel(const u16* __restrict__ yB,
                              const u16* __restrict__ w3, const u16* __restrict__ b3,
                              const u16* __restrict__ w5, const u16* __restrict__ b5,
                              const u16* __restrict__ w7, const u16* __restrict__ b7,
                              u16* __restrict__ fB) {
  constexpr int LW = 70, LH = 14, LP = 72;
  __shared__ u16 tile[LH * LP];
  __shared__ float wf7[49], wf5[25], wf3[9];
  const int t = threadIdx.x;
  const int c = blockIdx.y;
  const int tw = blockIdx.x & 3, th = blockIdx.x >> 2;
  const int w0 = tw * 64, h0 = th * 8;
  const u16* src = yB + (size_t)c * HW_;

  if (t < 49) wf7[t] = bf2f(w7[c * 49 + t]);
  if (t >= 64 && t < 89) wf5[t - 64] = bf2f(w5[c * 25 + (t - 64)]);
  if (t >= 96 && t < 105) wf3[t - 96] = bf2f(w3[c * 9 + (t - 96)]);

  for (int idx = t; idx < LH * LW; idx += 256) {
    const int r = idx / LW, cc = idx - r * LW;
    const int gh = h0 + r - 3, gw = w0 + cc - 3;
    u16 v = 0;
    if (gh >= 0 && gh < H_ && gw >= 0 && gw < W_) v = src[gh * W_ + gw];
    tile[r * LP + cc] = v;
  }
  __syncthreads();

  const int x0 = (t & 31) * 2;
  const int hh = t >> 5;
  float a3x = 0.f, a3y = 0.f, a5x = 0.f, a5y = 0.f, a7x = 0.f, a7y = 0.f;
#pragma unroll
  for (int rr = 0; rr < 7; ++rr) {
    const u16* trow = tile + (hh + rr) * LP + x0;
    float f[10];
#pragma unroll
    for (int k = 0; k < 5; ++k) {
      u32 v = *(const u32*)(trow + 2 * k);
      f[2 * k] = lo2f(v); f[2 * k + 1] = hi2f(v);
    }
#pragma unroll
    for (int dx = 0; dx < 7; ++dx) {
      const float wv = wf7[rr * 7 + dx];
      a7x += wv * f[dx]; a7y += wv * f[dx + 1];
    }
    if (rr >= 1 && rr <= 5) {
#pragma unroll
      for (int dx = 0; dx < 5; ++dx) {
        const float wv = wf5[(rr - 1) * 5 + dx];
        a5x += wv * f[dx + 1]; a5y += wv * f[dx + 2];
      }
    }
    if (rr >= 2 && rr <= 4) {
#pragma unroll
      for (int dx = 0; dx < 3; ++dx) {
        const float wv = wf3[(rr - 2) * 3 + dx];
        a3x += wv * f[dx + 2]; a3y += wv * f[dx + 3];
      }
    }
  }
  const float B3v = bf2f(b3[c]), B5v = bf2f(b5[c]), B7v = bf2f(b7[c]);
  const size_t o0 = (size_t)c * HW_ + (size_t)(h0 + hh) * W_ + (w0 + x0);
  *(u32*)(fB + o0) = (u32)f2bf(a3x + B3v) | ((u32)f2bf(a3y + B3v) << 16);
  *(u32*)(fB + o0 + (size_t)256 * HW_) = (u32)f2bf(a5x + B5v) | ((u32)f2bf(a5y + B5v) << 16);
  *(u32*)(fB + o0 + (size_t)512 * HW_) = (u32)f2bf(a7x + B7v) | ((u32)f2bf(a7y + B7v) << 16);
}

extern "C" void kernel_launch(void* const* d_in, const int* in_sizes, int n_in,
                              void* d_out, int out_size, void* d_ws, size_t ws_size,
                              hipStream_t stream) {
  (void)out_size; (void)ws_size; (void)n_in;
  char* ws = (char*)d_ws;
  const size_t MB = 1ull << 20;

  u16* arena = (u16*)ws;
  CvtArgs ca;
  u32 off = 0, blk = 0;
  u32 aoff[NT];
  for (int i = 0; i < NT; ++i) {
    ca.src[i] = d_in[i];
    ca.n[i] = (u32)in_sizes[i];
    ca.dst_off[i] = off;
    aoff[i] = off;
    ca.blk_start[i] = blk;
    off += (ca.n[i] + 15u) & ~15u;
    blk += (ca.n[i] + ELEMS_PER_BLK - 1) / ELEMS_PER_BLK;
  }
  const u32 total_blocks = blk;

  const u16* f1c   = arena + aoff[0];
  const u16* f2c   = arena + aoff[1];
  const u16* an_g  = arena + aoff[2];
  const u16* an_b  = arena + aoff[3];
  const u16* anc_g = arena + aoff[4];
  const u16* anc_b = arena + aoff[5];
  const u16* wq    = arena + aoff[6];
  const u16* bq    = arena + aoff[7];
  const u16* wkv   = arena + aoff[8];
  const u16* bkv   = arena + aoff[9];
  const u16* wo    = arena + aoff[10];
  const u16* bo    = arena + aoff[11];
  const u16* fn_g  = arena + aoff[12];
  const u16* fn_b  = arena + aoff[13];
  const u16* w_in  = arena + aoff[14];
  const u16* b_in  = arena + aoff[15];
  const u16* w3    = arena + aoff[16];
  const u16* b3    = arena + aoff[17];
  const u16* w5    = arena + aoff[18];
  const u16* b5    = arena + aoff[19];
  const u16* w7    = arena + aoff[20];
  const u16* b7    = arena + aoff[21];
  const u16* w_pw  = arena + aoff[22];
  const u16* b_pw  = arena + aoff[23];
  const u16* w_out = arena + aoff[24];
  const u16* b_out = arena + aoff[25];

  float* cat1r = (float*)(ws + 24 * MB);   // [24,56)  f32, K4 -> K5,K8
  u16* qb      = (u16*)(ws + 56 * MB);     // [56,72)  K1 -> K3
  u16* kvb     = (u16*)(ws + 72 * MB);     // [72,104) K2 -> K3
  u16* obf     = (u16*)(ws + 104 * MB);    // [104,120) K3 -> K4
  u16* yb      = (u16*)(ws + 56 * MB);     // [56,88)  K5 -> K6,K7
  u16* fbuf_b  = (u16*)(ws + 88 * MB);     // [88,114) per-batch (25.17MB)
  u16* y2b     = (u16*)(ws + 114 * MB);    // [114,146) K7 -> K8
  float* outp  = (float*)d_out;

  dim3 blk256(256);
  convert_all<<<total_blocks, 256, 0, stream>>>(ca, arena);

  // K1: q = wq @ LN(cat1; an)
  gemm1x1_mfma<128, 128, 1, true, false, false, 0, false>
      <<<dim3(HW_ / 64, 4), blk256, 0, stream>>>(f1c, f2c, wq, bq, an_g, an_b, 1e-6f,
                                                 nullptr, nullptr, qb, 0);
  // K2: kv = wkv @ LN(cat2; anc)
  gemm1x1_mfma<128, 256, 1, true, false, false, 0, false>
      <<<dim3(HW_ / 64, 4), blk256, 0, stream>>>(f2c, f1c, wkv, bkv, anc_g, anc_b, 1e-6f,
                                                 nullptr, nullptr, kvb, 0);
  // K3: attention (MFMA)
  attn_mfma<<<dim3(64, 4, 4), blk256, 0, stream>>>(qb, kvb, obf);
  // K4: cat1r = wo @ o + bo + cat1(f32 originals)
  gemm1x1_mfma<128, 128, 1, false, false, false, 4, true>
      <<<dim3(HW_ / 64, 4), blk256, 0, stream>>>(obf, nullptr, wo, bo, nullptr, nullptr, 0.f,
                                                 d_in[0], d_in[1], cat1r, 0);
  // K5: y = silu(w_in @ LN(cat1r; fn))
  gemm1x1_mfma<128, 256, 1, true, true, true, 0, false>
      <<<dim3(HW_ / 64, 4), blk256, 0, stream>>>(cat1r, nullptr, w_in, b_in, fn_g, fn_b, 1e-5f,
                                                 nullptr, nullptr, yb, 0);
  // K6/K7 per batch (K7: NOG=1 -> MT=4, 4x B-frag amortization)
  for (int b = 0; b < 4; ++b) {
    dwconv_kernel<<<dim3(32, 256), blk256, 0, stream>>>(yb + (size_t)b * 256 * HW_,
                                                        w3, b3, w5, b5, w7, b7, fbuf_b);
    gemm1x1_mfma<768, 256, 1, false, true, false, 2, false>
        <<<dim3(HW_ / 64, 1, 1), blk256, 0, stream>>>(fbuf_b, nullptr, w_pw, b_pw,
                                                      nullptr, nullptr, 0.f,
                                                      yb, nullptr, y2b, b);
  }
  // K8: out(f32) = cat1r + w_out @ y2 + b_out
  gemm1x1_mfma<256, 128, 1, false, false, false, 3, true>
      <<<dim3(HW_ / 64, 4), blk256, 0, stream>>>(y2b, nullptr, w_out, b_out,
                                                 nullptr, nullptr, 0.f,
                                                 cat1r, nullptr, outp, 0);
}